// Round 11
// baseline (287.228 us; speedup 1.0000x reference)
//
#include <hip/hip_runtime.h>
#include <hip/hip_bf16.h>
#include <cstdint>

#define S_LEN 2048
#define HIDDEN 2560
#define NH 32
#define NKV 8
#define HD 128
#define GS 128

typedef __attribute__((ext_vector_type(8))) _Float16 half8v;    // 8 x fp16
typedef __attribute__((ext_vector_type(2))) _Float16 half2v;    // 2 x fp16
typedef __attribute__((ext_vector_type(4))) float f32x4;
typedef unsigned int uint;
typedef unsigned short ushort;

__device__ inline ushort f2h(float f) {
    _Float16 h = (_Float16)f;
    return __builtin_bit_cast(ushort, h);
}
__device__ inline float h2f(ushort u) {
    return (float)__builtin_bit_cast(_Float16, u);
}
__device__ inline uint pk2(ushort a, ushort b) { return (uint)a | ((uint)b << 16); }

// async global->LDS, 16B per lane; lds base must be wave-uniform
__device__ __attribute__((always_inline)) inline void gl_lds16(const void* g, void* l) {
    __builtin_amdgcn_global_load_lds(
        (const __attribute__((address_space(1))) unsigned int*)g,
        (__attribute__((address_space(3))) unsigned int*)l, 16, 0, 0);
}

// ---------------------------------------------------------------------------
// X -> fp16. One block per row, 320 thr x 8 els.
// ---------------------------------------------------------------------------
__global__ __launch_bounds__(320) void xcvt_kernel(
    const float* __restrict__ X, ushort* __restrict__ Xf)
{
    const int row = blockIdx.x;
    const int t   = threadIdx.x;
    const size_t base = (size_t)row * HIDDEN + t * 8;
    float4 a = *(const float4*)&X[base];
    float4 b = *(const float4*)&X[base + 4];
    uint4 hw = {pk2(f2h(a.x), f2h(a.y)), pk2(f2h(a.z), f2h(a.w)),
                pk2(f2h(b.x), f2h(b.y)), pk2(f2h(b.z), f2h(b.w))};
    *(uint4*)&Xf[base] = hw;
}

// ===========================================================================
// Fused Q/K/V AWQ-int4 MFMA GEMM, fp16 direct-scaled B, 256-thread blocks.
// Block 128Mx128N, 4 waves (2Mx2N), wave tile 64x64.
// LDS: A dbuf 2x16KB + B single 16KB = 48 KB -> 3 blocks/CU (cross-block
// overlap hides barrier vmcnt drains; VGPR ~100 allows 16 waves/CU).
// enc = fp16(128+nib) = 0x5800 | nib<<3 (exact);
// w = pk_fma(enc, sc_h, -128*sc_h) + (-z*sc_h).
// N-tile == one head for Q/K: wave col remap keeps RoPE partners intra-lane:
//   ncm[nf] = wc*32 + (nf&1)*16 + lr + (nf>=2 ? 64 : 0)
// ===========================================================================
__global__ __launch_bounds__(256) void qkv6_kernel(
    const ushort* __restrict__ Xf,
    const int* __restrict__ q_qw, const float* __restrict__ q_sc,
    const int* __restrict__ q_qz, const float* __restrict__ q_b,
    const int* __restrict__ k_qw, const float* __restrict__ k_sc,
    const int* __restrict__ k_qz, const float* __restrict__ k_b,
    const int* __restrict__ v_qw, const float* __restrict__ v_sc,
    const int* __restrict__ v_qz, const float* __restrict__ v_b,
    const float* __restrict__ cosb, const float* __restrict__ sinb,
    ushort* __restrict__ Qf, ushort* __restrict__ Kf,
    ushort* __restrict__ Vrm)
{
    __shared__ __align__(16) char LDSB[49152];
    ushort* A0 = (ushort*)(LDSB);
    ushort* A1 = (ushort*)(LDSB + 16384);
    ushort* Bt = (ushort*)(LDSB + 32768);   // 16 KB, single buffer

    const int t  = threadIdx.x;
    const int w  = t >> 6;        // 0..3
    const int l  = t & 63;
    const int lg = l >> 4;
    const int lr = l & 15;
    const int wr = w >> 1;        // M half
    const int wc = w & 1;         // N half
    const int K  = HIDDEN;

    // XCD-bijective swizzle: 768 = 8 * 96; n-index fastest (A-band L2 reuse)
    const int bid = blockIdx.x;
    const int swz = (bid & 7) * 96 + (bid >> 3);
    const int nblk = swz % 48;
    const int m0   = (swz / 48) * 128;

    int region, nbase, Nw;
    const int* QW; const float* SC; const int* QZ; const float* BI;
    if (nblk < 32)      { region = 0; nbase = nblk * 128;        Nw = NH * HD;
                          QW = q_qw; SC = q_sc; QZ = q_qz; BI = q_b; }
    else if (nblk < 40) { region = 1; nbase = (nblk - 32) * 128; Nw = NKV * HD;
                          QW = k_qw; SC = k_sc; QZ = k_qz; BI = k_b; }
    else                { region = 2; nbase = (nblk - 40) * 128; Nw = NKV * HD;
                          QW = v_qw; SC = v_sc; QZ = v_qz; BI = v_b; }

    // A staging: 4 chunks of 16B per thread (128 rows x 64 k fp16 = 16 KB)
    const int ldsAw = w * 1024;   // wave-uniform within each i*4096 stripe
    size_t aoff[4];
#pragma unroll
    for (int i = 0; i < 4; ++i) {
        int slot = i * 256 + t;
        int am = slot >> 3, ac = slot & 7;
        aoff[i] = (size_t)(m0 + am) * K + (size_t)((ac ^ (am & 7)) * 8);
    }
    // B staging (4 qwords per thread: col bn, krows bk0..bk0+3)
    const int bn  = t & 127;
    const int bk0 = (t >> 7) * 4;
    int bwoff[4];
#pragma unroll
    for (int j = 0; j < 4; ++j)
        bwoff[j] = (bn * 128 + (bk0 + j) * 16) ^ ((bn & 7) << 4);

    // wave col remap (RoPE partners intra-lane)
    int ncm[4];
#pragma unroll
    for (int nf = 0; nf < 4; ++nf)
        ncm[nf] = wc * 32 + (nf & 1) * 16 + lr + ((nf & 2) ? 64 : 0);

    const int xorA = (lr & 7) << 4;
    int aroff[4][2], broff[4][2];
#pragma unroll
    for (int mf = 0; mf < 4; ++mf)
#pragma unroll
        for (int ks = 0; ks < 2; ++ks)
            aroff[mf][ks] = (((wr * 64 + mf * 16 + lr) * 128) + lg * 16 + ks * 64) ^ xorA;
#pragma unroll
    for (int nf = 0; nf < 4; ++nf)
#pragma unroll
        for (int ks = 0; ks < 2; ++ks)
            broff[nf][ks] = ((ncm[nf] * 128) + lg * 16 + ks * 64) ^ xorA;

    f32x4 macc[4][4];
#pragma unroll
    for (int mf = 0; mf < 4; ++mf)
#pragma unroll
        for (int nf = 0; nf < 4; ++nf) macc[mf][nf] = f32x4{0.f, 0.f, 0.f, 0.f};
    uint qr[4];
    float scf, zf;

#define QKV_QW(tile) { int g8 = (tile) * 8; int gg = (tile) >> 1; \
    _Pragma("unroll") \
    for (int j = 0; j < 4; ++j) \
        qr[j] = (uint)QW[(size_t)(g8 + bk0 + j) * Nw + nbase + bn]; \
    scf = SC[(size_t)gg * Nw + nbase + bn]; \
    zf  = (float)QZ[(size_t)gg * Nw + nbase + bn]; }

#define QKV_STAGE_A(AH, k0) { \
    gl_lds16(Xf + (k0) + aoff[0], (char*)(AH) + ldsAw); \
    gl_lds16(Xf + (k0) + aoff[1], (char*)(AH) + 4096 + ldsAw); \
    gl_lds16(Xf + (k0) + aoff[2], (char*)(AH) + 8192 + ldsAw); \
    gl_lds16(Xf + (k0) + aoff[3], (char*)(AH) + 12288 + ldsAw); }

#define QKV_BWRITE(BT) { \
    ushort sch = f2h(scf); \
    float schf = h2f(sch); \
    ushort msc = f2h(-128.0f * schf);   /* exact exponent shift */ \
    ushort nzs = f2h(-(zf * schf)); \
    half2v S2 = {__builtin_bit_cast(_Float16, sch), __builtin_bit_cast(_Float16, sch)}; \
    half2v M2 = {__builtin_bit_cast(_Float16, msc), __builtin_bit_cast(_Float16, msc)}; \
    half2v Z2 = {__builtin_bit_cast(_Float16, nzs), __builtin_bit_cast(_Float16, nzs)}; \
    _Pragma("unroll") \
    for (int j = 0; j < 4; ++j) { \
        uint q = qr[j]; \
        uint b0 = q & 0xFFu, b1 = (q >> 8) & 0xFFu, b2 = (q >> 16) & 0xFFu, b3 = q >> 24; \
        uint e0 = 0x58005800u | ((b0 & 0xFu) << 3) | ((b0 & 0xF0u) << 15); \
        uint e1 = 0x58005800u | ((b1 & 0xFu) << 3) | ((b1 & 0xF0u) << 15); \
        uint e2 = 0x58005800u | ((b2 & 0xFu) << 3) | ((b2 & 0xF0u) << 15); \
        uint e3 = 0x58005800u | ((b3 & 0xFu) << 3) | ((b3 & 0xF0u) << 15); \
        half2v w0 = __builtin_bit_cast(half2v, e0) * S2 + M2; w0 = w0 + Z2; \
        half2v w1 = __builtin_bit_cast(half2v, e1) * S2 + M2; w1 = w1 + Z2; \
        half2v w2 = __builtin_bit_cast(half2v, e2) * S2 + M2; w2 = w2 + Z2; \
        half2v w3 = __builtin_bit_cast(half2v, e3) * S2 + M2; w3 = w3 + Z2; \
        uint4 dw = {__builtin_bit_cast(uint, w0), __builtin_bit_cast(uint, w1), \
                    __builtin_bit_cast(uint, w2), __builtin_bit_cast(uint, w3)}; \
        *(uint4*)((char*)(BT) + bwoff[j]) = dw; \
    } }

#define QKV_COMPUTE(AH, BT) { \
    _Pragma("unroll") \
    for (int ks = 0; ks < 2; ++ks) { \
        half8v av[4], bv[4]; \
        _Pragma("unroll") \
        for (int mf = 0; mf < 4; ++mf) \
            av[mf] = *(const half8v*)((const char*)(AH) + aroff[mf][ks]); \
        _Pragma("unroll") \
        for (int nf = 0; nf < 4; ++nf) \
            bv[nf] = *(const half8v*)((const char*)(BT) + broff[nf][ks]); \
        _Pragma("unroll") \
        for (int mf = 0; mf < 4; ++mf) \
            _Pragma("unroll") \
            for (int nf = 0; nf < 4; ++nf) \
                macc[mf][nf] = __builtin_amdgcn_mfma_f32_16x16x32_f16(av[mf], bv[nf], macc[mf][nf], 0, 0, 0); \
    } }

    // prologue: tile 0 in Bt/A0; tile-1 QW words in flight
    QKV_QW(0);
    QKV_BWRITE(Bt);
    QKV_STAGE_A(A0, 0);
    QKV_QW(1);
    __syncthreads();

    for (int g = 0; g < 20; ++g) {
        QKV_COMPUTE(A0, Bt);                 // tile 2g
        __syncthreads();
        QKV_BWRITE(Bt);                      // tile 2g+1 (qr loaded 1 tile ago)
        QKV_STAGE_A(A1, (2 * g + 1) * 64);
        if (g < 19) QKV_QW(2 * g + 2);
        __syncthreads();
        QKV_COMPUTE(A1, Bt);                 // tile 2g+1
        __syncthreads();
        if (g < 19) {
            QKV_BWRITE(Bt);                  // tile 2g+2
            QKV_STAGE_A(A0, (2 * g + 2) * 64);
            QKV_QW(2 * g + 3);
        }
        __syncthreads();
    }

    // ---- +bias ----
#pragma unroll
    for (int nf = 0; nf < 4; ++nf) {
        float bv = BI[nbase + ncm[nf]];
#pragma unroll
        for (int mf = 0; mf < 4; ++mf)
#pragma unroll
            for (int r = 0; r < 4; ++r) macc[mf][nf][r] += bv;
    }

    // ---- epilogue ----
    if (region == 2) {
#pragma unroll
        for (int mf = 0; mf < 4; ++mf)
#pragma unroll
            for (int r = 0; r < 4; ++r) {
                int row = m0 + wr * 64 + mf * 16 + lg * 4 + r;
#pragma unroll
                for (int nf = 0; nf < 4; ++nf)
                    Vrm[(size_t)row * (NKV * HD) + nbase + ncm[nf]] = f2h(macc[mf][nf][r]);
            }
    } else {
        ushort* OF = (region == 0) ? Qf : Kf;
        const int No = (region == 0) ? NH * HD : NKV * HD;
        const float osc = (region == 0) ? 0.08838834764831845f : 1.0f;
#pragma unroll
        for (int mf = 0; mf < 4; ++mf)
#pragma unroll
            for (int r = 0; r < 4; ++r) {
                int row = m0 + wr * 64 + mf * 16 + lg * 4 + r;
                const float* cb = &cosb[(size_t)row * HD];
                const float* sb = &sinb[(size_t)row * HD];
#pragma unroll
                for (int nf = 0; nf < 2; ++nf) {
                    int d = wc * 32 + nf * 16 + lr;           // 0..63
                    float a = macc[mf][nf][r];
                    float b = macc[mf][nf + 2][r];
                    float o1 = (a * cb[d]      - b * sb[d])      * osc;
                    float o2 = (b * cb[d + 64] + a * sb[d + 64]) * osc;
                    OF[(size_t)row * No + nbase + d]      = f2h(o1);
                    OF[(size_t)row * No + nbase + d + 64] = f2h(o2);
                }
            }
    }
#undef QKV_QW
#undef QKV_STAGE_A
#undef QKV_BWRITE
#undef QKV_COMPUTE
}

// ---------------------------------------------------------------------------
// V transpose: Vrm [S][1024] fp16 -> VfT [1024][S]. 64x64 LDS tiles.
// ---------------------------------------------------------------------------
__global__ __launch_bounds__(256) void vtrans_kernel(
    const ushort* __restrict__ Vrm, ushort* __restrict__ VfT)
{
    __shared__ ushort Ts[64][65];
    const int s0 = blockIdx.x * 64;
    const int n0 = blockIdx.y * 64;
    const int t  = threadIdx.x;
    {
        int r = t >> 2, c0 = (t & 3) * 16;
        uint4 v0 = *(const uint4*)&Vrm[(size_t)(s0 + r) * (NKV * HD) + n0 + c0];
        uint4 v1 = *(const uint4*)&Vrm[(size_t)(s0 + r) * (NKV * HD) + n0 + c0 + 8];
        const ushort* pv = (const ushort*)&v0;
#pragma unroll
        for (int j = 0; j < 8; ++j) Ts[r][c0 + j] = pv[j];
        pv = (const ushort*)&v1;
#pragma unroll
        for (int j = 0; j < 8; ++j) Ts[r][c0 + 8 + j] = pv[j];
    }
    __syncthreads();
    {
        int rn = t >> 2, cs0 = (t & 3) * 16;
        ushort ob[16];
#pragma unroll
        for (int j = 0; j < 16; ++j) ob[j] = Ts[cs0 + j][rn];
        ushort* dst = &VfT[(size_t)(n0 + rn) * S_LEN + s0 + cs0];
        *(uint4*)dst = ((uint4*)ob)[0];
        *(uint4*)(dst + 8) = ((uint4*)ob)[1];
    }
}

// ===========================================================================
// O-projection, fp16 direct-scaled B, 256-thread blocks.
// Block 128Mx128N, 4 waves (2Mx2N), wave tile 64x64.
// LDS: A dbuf 32KB + B single 16KB = 48 KB -> 3 blocks/CU. Grid 320.
// ===========================================================================
__global__ __launch_bounds__(256) void oproj5_kernel(
    const ushort* __restrict__ Xb, const int* __restrict__ QW,
    const float* __restrict__ SC, const int* __restrict__ QZ,
    float* __restrict__ Y)
{
    __shared__ __align__(16) char LDSB[49152];
    ushort* A0 = (ushort*)(LDSB);
    ushort* A1 = (ushort*)(LDSB + 16384);
    ushort* Bt = (ushort*)(LDSB + 32768);

    const int t  = threadIdx.x;
    const int w  = t >> 6;
    const int l  = t & 63;
    const int lg = l >> 4;
    const int lr = l & 15;
    const int wr = w >> 1;
    const int wc = w & 1;
    const int K  = NH * HD;      // 4096
    const int N  = HIDDEN;       // 2560

    const int bid = blockIdx.x;
    const int swz = (bid & 7) * 40 + (bid >> 3);   // 320 = 8*40
    const int n0  = (swz % 20) * 128;
    const int m0  = (swz / 20) * 128;

    const int ldsAw = w * 1024;
    size_t aoff[4];
#pragma unroll
    for (int i = 0; i < 4; ++i) {
        int slot = i * 256 + t;
        int am = slot >> 3, ac = slot & 7;
        aoff[i] = (size_t)(m0 + am) * K + (size_t)((ac ^ (am & 7)) * 8);
    }
    const int bn  = t & 127;
    const int bk0 = (t >> 7) * 4;
    int bwoff[4];
#pragma unroll
    for (int j = 0; j < 4; ++j)
        bwoff[j] = (bn * 128 + (bk0 + j) * 16) ^ ((bn & 7) << 4);

    const int xorA = (lr & 7) << 4;
    int aroff[4][2], broff[4][2];
#pragma unroll
    for (int mf = 0; mf < 4; ++mf)
#pragma unroll
        for (int ks = 0; ks < 2; ++ks)
            aroff[mf][ks] = (((wr * 64 + mf * 16 + lr) * 128) + lg * 16 + ks * 64) ^ xorA;
#pragma unroll
    for (int nf = 0; nf < 4; ++nf)
#pragma unroll
        for (int ks = 0; ks < 2; ++ks)
            broff[nf][ks] = (((wc * 64 + nf * 16 + lr) * 128) + lg * 16 + ks * 64) ^ xorA;

    f32x4 macc[4][4];
#pragma unroll
    for (int mf = 0; mf < 4; ++mf)
#pragma unroll
        for (int nf = 0; nf < 4; ++nf) macc[mf][nf] = f32x4{0.f, 0.f, 0.f, 0.f};
    uint qr[4];
    float scf, zf;

#define OP_QW(tile) { int g8 = (tile) * 8; int gg = (tile) >> 1; \
    _Pragma("unroll") \
    for (int j = 0; j < 4; ++j) \
        qr[j] = (uint)QW[(size_t)(g8 + bk0 + j) * N + n0 + bn]; \
    scf = SC[(size_t)gg * N + n0 + bn]; \
    zf  = (float)QZ[(size_t)gg * N + n0 + bn]; }

#define OP_STAGE_A(AH, k0) { \
    gl_lds16(Xb + (k0) + aoff[0], (char*)(AH) + ldsAw); \
    gl_lds16(Xb + (k0) + aoff[1], (char*)(AH) + 4096 + ldsAw); \
    gl_lds16(Xb + (k0) + aoff[2], (char*)(AH) + 8192 + ldsAw); \
    gl_lds16(Xb + (k0) + aoff[3], (char*)(AH) + 12288 + ldsAw); }

#define OP_BWRITE(BT) { \
    ushort sch = f2h(scf); \
    float schf = h2f(sch); \
    ushort msc = f2h(-128.0f * schf); \
    ushort nzs = f2h(-(zf * schf)); \
    half2v S2 = {__builtin_bit_cast(_Float16, sch), __builtin_bit_cast(_Float16, sch)}; \
    half2v M2 = {__builtin_bit_cast(_Float16, msc), __builtin_bit_cast(_Float16, msc)}; \
    half2v Z2 = {__builtin_bit_cast(_Float16, nzs), __builtin_bit_cast(_Float16, nzs)}; \
    _Pragma("unroll") \
    for (int j = 0; j < 4; ++j) { \
        uint q = qr[j]; \
        uint b0 = q & 0xFFu, b1 = (q >> 8) & 0xFFu, b2 = (q >> 16) & 0xFFu, b3 = q >> 24; \
        uint e0 = 0x58005800u | ((b0 & 0xFu) << 3) | ((b0 & 0xF0u) << 15); \
        uint e1 = 0x58005800u | ((b1 & 0xFu) << 3) | ((b1 & 0xF0u) << 15); \
        uint e2 = 0x58005800u | ((b2 & 0xFu) << 3) | ((b2 & 0xF0u) << 15); \
        uint e3 = 0x58005800u | ((b3 & 0xFu) << 3) | ((b3 & 0xF0u) << 15); \
        half2v w0 = __builtin_bit_cast(half2v, e0) * S2 + M2; w0 = w0 + Z2; \
        half2v w1 = __builtin_bit_cast(half2v, e1) * S2 + M2; w1 = w1 + Z2; \
        half2v w2 = __builtin_bit_cast(half2v, e2) * S2 + M2; w2 = w2 + Z2; \
        half2v w3 = __builtin_bit_cast(half2v, e3) * S2 + M2; w3 = w3 + Z2; \
        uint4 dw = {__builtin_bit_cast(uint, w0), __builtin_bit_cast(uint, w1), \
                    __builtin_bit_cast(uint, w2), __builtin_bit_cast(uint, w3)}; \
        *(uint4*)((char*)(BT) + bwoff[j]) = dw; \
    } }

#define OP_COMPUTE(AH, BT) { \
    _Pragma("unroll") \
    for (int ks = 0; ks < 2; ++ks) { \
        half8v av[4], bv[4]; \
        _Pragma("unroll") \
        for (int mf = 0; mf < 4; ++mf) \
            av[mf] = *(const half8v*)((const char*)(AH) + aroff[mf][ks]); \
        _Pragma("unroll") \
        for (int nf = 0; nf < 4; ++nf) \
            bv[nf] = *(const half8v*)((const char*)(BT) + broff[nf][ks]); \
        _Pragma("unroll") \
        for (int mf = 0; mf < 4; ++mf) \
            _Pragma("unroll") \
            for (int nf = 0; nf < 4; ++nf) \
                macc[mf][nf] = __builtin_amdgcn_mfma_f32_16x16x32_f16(av[mf], bv[nf], macc[mf][nf], 0, 0, 0); \
    } }

    OP_QW(0);
    OP_BWRITE(Bt);
    OP_STAGE_A(A0, 0);
    OP_QW(1);
    __syncthreads();

    for (int g = 0; g < 32; ++g) {
        OP_COMPUTE(A0, Bt);                  // tile 2g
        __syncthreads();
        OP_BWRITE(Bt);                       // tile 2g+1
        OP_STAGE_A(A1, (2 * g + 1) * 64);
        if (g < 31) OP_QW(2 * g + 2);
        __syncthreads();
        OP_COMPUTE(A1, Bt);                  // tile 2g+1
        __syncthreads();
        if (g < 31) {
            OP_BWRITE(Bt);                   // tile 2g+2
            OP_STAGE_A(A0, (2 * g + 2) * 64);
            OP_QW(2 * g + 3);
        }
        __syncthreads();
    }

#pragma unroll
    for (int mf = 0; mf < 4; ++mf)
#pragma unroll
        for (int r = 0; r < 4; ++r) {
            int row = m0 + wr * 64 + mf * 16 + lg * 4 + r;
#pragma unroll
            for (int nf = 0; nf < 4; ++nf)
                Y[(size_t)row * N + n0 + wc * 64 + nf * 16 + lr] = macc[mf][nf][r];
        }
#undef OP_QW
#undef OP_STAGE_A
#undef OP_BWRITE
#undef OP_COMPUTE
}

// ---------------------------------------------------------------------------
// Causal GQA flash attention, fp16 MFMA, swapped operands (unchanged r10).
// ---------------------------------------------------------------------------
__global__ __launch_bounds__(256) void attn_mfma_kernel(
    const ushort* __restrict__ Qh,   // [S][NH*HD] fp16, roped, *1/sqrt(HD)
    const ushort* __restrict__ Kh,   // [S][NKV*HD] fp16, roped
    const ushort* __restrict__ Vt,   // [NKV*HD][S] fp16 (transposed)
    ushort* __restrict__ AO)         // [S][NH*HD] fp16
{
    __shared__ ushort KsF[32 * 128];           // 8 KB, swz ^((row&7)<<4)
    __shared__ ushort Vs[128 * 32];            // 8 KB, swz ^((dim&3)<<4)
    __shared__ __align__(16) char PsB[4 * 1280];  // P: 16 rows x 80B per wave

    const int h  = blockIdx.x;
    const int qb = gridDim.y - 1 - blockIdx.y;
    const int s0 = qb * 64;
    const int t  = threadIdx.x;
    const int w  = t >> 6;
    const int l  = t & 63;
    const int lg = l >> 4;
    const int lr = l & 15;
    const int kvh = h >> 2;
    const int qw = s0 + w * 16;
    const int q  = qw + lr;          // this lane's q-row

    half8v qf[4];
#pragma unroll
    for (int d = 0; d < 4; ++d) {
        size_t off = (size_t)q * (NH * HD) + h * HD + d * 32 + lg * 8;
        qf[d] = *(const half8v*)&Qh[off];
    }

    f32x4 o[8];
#pragma unroll
    for (int i = 0; i < 8; ++i) o[i] = f32x4{0.f, 0.f, 0.f, 0.f};
    float m = -1e30f, lsum = 0.f;
    char* pw = PsB + w * 1280;

    const int ntiles = qb * 2 + 2;
    for (int kt = 0; kt < ntiles; ++kt) {
        const int k0 = kt * 32;
#pragma unroll
        for (int i = 0; i < 2; ++i) {
            int slot = w * 128 + i * 64 + l;
            int mr = slot >> 4, c = slot & 15;
            size_t goff = (size_t)(k0 + mr) * (NKV * HD) + kvh * HD + ((c ^ (mr & 7)) * 8);
            gl_lds16(Kh + goff, (char*)KsF + (w * 128 + i * 64) * 16);
        }
#pragma unroll
        for (int i = 0; i < 2; ++i) {
            int slot = w * 128 + i * 64 + l;
            int dim = slot >> 2, c = slot & 3;
            size_t goff = (size_t)(kvh * HD + dim) * S_LEN + k0 + ((c ^ (dim & 3)) * 8);
            gl_lds16(Vt + goff, (char*)Vs + (w * 128 + i * 64) * 16);
        }
        __syncthreads();

        if (k0 <= qw + 15) {   // wave-uniform causal skip
            f32x4 s[2];
            s[0] = f32x4{0.f, 0.f, 0.f, 0.f};
            s[1] = f32x4{0.f, 0.f, 0.f, 0.f};
#pragma unroll
            for (int d = 0; d < 4; ++d) {
#pragma unroll
                for (int nt2 = 0; nt2 < 2; ++nt2) {
                    int row = nt2 * 16 + lr;
                    int off = row * 256 + ((d * 64 + lg * 16) ^ ((row & 7) << 4));
                    half8v kf = *(const half8v*)((char*)KsF + off);
                    s[nt2] = __builtin_amdgcn_mfma_f32_16x16x32_f16(kf, qf[d], s[nt2], 0, 0, 0);
                }
            }
            float sv[8];
#pragma unroll
            for (int nt2 = 0; nt2 < 2; ++nt2)
#pragma unroll
                for (int r = 0; r < 4; ++r) {
                    int kv = k0 + nt2 * 16 + lg * 4 + r;
                    sv[nt2 * 4 + r] = (kv <= q) ? s[nt2][r] : -1e30f;
                }
            float mx = sv[0];
#pragma unroll
            for (int j = 1; j < 8; ++j) mx = fmaxf(mx, sv[j]);
            mx = fmaxf(mx, __shfl_xor(mx, 16));
            mx = fmaxf(mx, __shfl_xor(mx, 32));
            float mnew = fmaxf(m, mx);
            float resc = __expf(m - mnew);
            m = mnew;
            float p[8], ps = 0.f;
#pragma unroll
            for (int j = 0; j < 8; ++j) { p[j] = __expf(sv[j] - mnew); ps += p[j]; }
            ps += __shfl_xor(ps, 16);
            ps += __shfl_xor(ps, 32);
            lsum = lsum * resc + ps;
#pragma unroll
            for (int dt = 0; dt < 8; ++dt)
#pragma unroll
                for (int r = 0; r < 4; ++r) o[dt][r] *= resc;
            uint2 w0 = {pk2(f2h(p[0]), f2h(p[1])), pk2(f2h(p[2]), f2h(p[3]))};
            uint2 w1 = {pk2(f2h(p[4]), f2h(p[5])), pk2(f2h(p[6]), f2h(p[7]))};
            *(uint2*)(pw + lr * 80 + lg * 8)      = w0;
            *(uint2*)(pw + lr * 80 + 32 + lg * 8) = w1;
            asm volatile("s_waitcnt lgkmcnt(0)" ::: "memory");
            half8v pf = *(const half8v*)(pw + lr * 80 + lg * 16);
#pragma unroll
            for (int dt = 0; dt < 8; ++dt) {
                int dim = dt * 16 + lr;
                half8v vf = *(const half8v*)((char*)Vs + dim * 64 + ((lg * 16) ^ ((dim & 3) << 4)));
                o[dt] = __builtin_amdgcn_mfma_f32_16x16x32_f16(vf, pf, o[dt], 0, 0, 0);
            }
        }
        __syncthreads();
    }

    float inv = 1.f / lsum;
    ushort* dst = &AO[(size_t)q * (NH * HD) + h * HD];
#pragma unroll
    for (int dt = 0; dt < 8; ++dt) {
        uint2 ov = {pk2(f2h(o[dt][0] * inv), f2h(o[dt][1] * inv)),
                    pk2(f2h(o[dt][2] * inv), f2h(o[dt][3] * inv))};
        *(uint2*)(dst + dt * 16 + lg * 4) = ov;
    }
}

// ---------------------------------------------------------------------------
extern "C" void kernel_launch(void* const* d_in, const int* in_sizes, int n_in,
                              void* d_out, int out_size, void* d_ws, size_t ws_size,
                              hipStream_t stream)
{
    const float* x    = (const float*)d_in[0];
    const float* cosb = (const float*)d_in[1];
    const float* sinb = (const float*)d_in[2];
    const float* q_sc = (const float*)d_in[3];
    const float* q_b  = (const float*)d_in[4];
    const float* k_sc = (const float*)d_in[5];
    const float* k_b  = (const float*)d_in[6];
    const float* v_sc = (const float*)d_in[7];
    const float* v_b  = (const float*)d_in[8];
    const float* o_sc = (const float*)d_in[9];
    const int* q_qw   = (const int*)d_in[10];
    const int* q_qz   = (const int*)d_in[11];
    const int* k_qw   = (const int*)d_in[12];
    const int* k_qz   = (const int*)d_in[13];
    const int* v_qw   = (const int*)d_in[14];
    const int* v_qz   = (const int*)d_in[15];
    const int* o_qw   = (const int*)d_in[16];
    const int* o_qz   = (const int*)d_in[17];
    float* out = (float*)d_out;

    // ws layout (MB):
    //   0:  Xf16 (10)  [aliased by AOf16 (16) after qkv6]
    //   16: Qf (16) | 32: Kf (4) | 36: Vrm (4) | 40: VfT (4)
    char* ws = (char*)d_ws;
    ushort* Xf   = (ushort*)ws;
    ushort* AOf  = (ushort*)ws;                                  // alias
    ushort* Qf   = (ushort*)(ws + (size_t)16 * 1024 * 1024);
    ushort* Kf   = (ushort*)(ws + (size_t)32 * 1024 * 1024);
    ushort* Vrm  = (ushort*)(ws + (size_t)36 * 1024 * 1024);
    ushort* VfT  = (ushort*)(ws + (size_t)40 * 1024 * 1024);

    xcvt_kernel<<<S_LEN, 320, 0, stream>>>(x, Xf);

    qkv6_kernel<<<768, 256, 0, stream>>>(
        Xf,
        q_qw, q_sc, q_qz, q_b,
        k_qw, k_sc, k_qz, k_b,
        v_qw, v_sc, v_qz, v_b,
        cosb, sinb, Qf, Kf, Vrm);

    vtrans_kernel<<<dim3(S_LEN / 64, (NKV * HD) / 64), 256, 0, stream>>>(Vrm, VfT);

    attn_mfma_kernel<<<dim3(NH, S_LEN / 64), 256, 0, stream>>>(Qf, Kf, VfT, AOf);

    oproj5_kernel<<<320, 256, 0, stream>>>(
        AOf, o_qw, o_sc, o_qz, out);
}

// Round 12
// 265.595 us; speedup vs baseline: 1.0814x; 1.0814x over previous
//
#include <hip/hip_runtime.h>
#include <hip/hip_bf16.h>
#include <cstdint>

#define S_LEN 2048
#define HIDDEN 2560
#define NH 32
#define NKV 8
#define HD 128
#define GS 128

typedef __attribute__((ext_vector_type(8))) _Float16 half8v;    // 8 x fp16
typedef __attribute__((ext_vector_type(2))) _Float16 half2v;    // 2 x fp16
typedef __attribute__((ext_vector_type(4))) float f32x4;
typedef unsigned int uint;
typedef unsigned short ushort;

__device__ inline ushort f2h(float f) {
    _Float16 h = (_Float16)f;
    return __builtin_bit_cast(ushort, h);
}
__device__ inline float h2f(ushort u) {
    return (float)__builtin_bit_cast(_Float16, u);
}
__device__ inline uint pk2(ushort a, ushort b) { return (uint)a | ((uint)b << 16); }

// async global->LDS, 16B per lane; lds base must be wave-uniform
__device__ __attribute__((always_inline)) inline void gl_lds16(const void* g, void* l) {
    __builtin_amdgcn_global_load_lds(
        (const __attribute__((address_space(1))) unsigned int*)g,
        (__attribute__((address_space(3))) unsigned int*)l, 16, 0, 0);
}

// counted-waitcnt barrier helpers (T3+T4): raw s_barrier, no vmcnt(0) drain
#define WAIT_LGKM0  asm volatile("s_waitcnt lgkmcnt(0)" ::: "memory")
#define WAIT_VM(N)  asm volatile("s_waitcnt vmcnt(" #N ")" ::: "memory")
#define RAW_BARRIER { __builtin_amdgcn_s_barrier(); __builtin_amdgcn_sched_barrier(0); }

// ---------------------------------------------------------------------------
// X -> fp16. One block per row, 320 thr x 8 els.
// ---------------------------------------------------------------------------
__global__ __launch_bounds__(320) void xcvt_kernel(
    const float* __restrict__ X, ushort* __restrict__ Xf)
{
    const int row = blockIdx.x;
    const int t   = threadIdx.x;
    const size_t base = (size_t)row * HIDDEN + t * 8;
    float4 a = *(const float4*)&X[base];
    float4 b = *(const float4*)&X[base + 4];
    uint4 hw = {pk2(f2h(a.x), f2h(a.y)), pk2(f2h(a.z), f2h(a.w)),
                pk2(f2h(b.x), f2h(b.y)), pk2(f2h(b.z), f2h(b.w))};
    *(uint4*)&Xf[base] = hw;
}

// ===========================================================================
// Fused Q/K/V AWQ-int4 MFMA GEMM, fp16 direct-scaled B, counted-vmcnt
// pipeline (T3+T4): raw s_barrier, loads stay in flight across barriers.
// Per tile: enter {QW(t+1) 6 in flight} -> STAGE_A(t+1) (+4) -> COMPUTE ->
// BWRITE(B[(t+1)&1]) -> QW(t+2) (+6) -> lgkmcnt(0); vmcnt(6); s_barrier.
// Block 128Mx128N, 4 waves (2Mx2N), wave tile 64x64. LDS 64KB (A,B dbuf).
// ===========================================================================
__global__ __launch_bounds__(256) void qkv7_kernel(
    const ushort* __restrict__ Xf,
    const int* __restrict__ q_qw, const float* __restrict__ q_sc,
    const int* __restrict__ q_qz, const float* __restrict__ q_b,
    const int* __restrict__ k_qw, const float* __restrict__ k_sc,
    const int* __restrict__ k_qz, const float* __restrict__ k_b,
    const int* __restrict__ v_qw, const float* __restrict__ v_sc,
    const int* __restrict__ v_qz, const float* __restrict__ v_b,
    const float* __restrict__ cosb, const float* __restrict__ sinb,
    ushort* __restrict__ Qf, ushort* __restrict__ Kf,
    ushort* __restrict__ Vrm)
{
    __shared__ __align__(16) char LDSB[65536];
    ushort* A0 = (ushort*)(LDSB);
    ushort* A1 = (ushort*)(LDSB + 16384);
    ushort* B0 = (ushort*)(LDSB + 32768);
    ushort* B1 = (ushort*)(LDSB + 49152);

    const int t  = threadIdx.x;
    const int w  = t >> 6;        // 0..3
    const int l  = t & 63;
    const int lg = l >> 4;
    const int lr = l & 15;
    const int wr = w >> 1;        // M half
    const int wc = w & 1;         // N half
    const int K  = HIDDEN;

    // XCD-bijective swizzle: 768 = 8 * 96; n-index fastest (A-band L2 reuse)
    const int bid = blockIdx.x;
    const int swz = (bid & 7) * 96 + (bid >> 3);
    const int nblk = swz % 48;
    const int m0   = (swz / 48) * 128;

    int region, nbase, Nw;
    const int* QW; const float* SC; const int* QZ; const float* BI;
    if (nblk < 32)      { region = 0; nbase = nblk * 128;        Nw = NH * HD;
                          QW = q_qw; SC = q_sc; QZ = q_qz; BI = q_b; }
    else if (nblk < 40) { region = 1; nbase = (nblk - 32) * 128; Nw = NKV * HD;
                          QW = k_qw; SC = k_sc; QZ = k_qz; BI = k_b; }
    else                { region = 2; nbase = (nblk - 40) * 128; Nw = NKV * HD;
                          QW = v_qw; SC = v_sc; QZ = v_qz; BI = v_b; }

    // A staging: 4 chunks of 16B per thread
    const int ldsAw = w * 1024;
    size_t aoff[4];
#pragma unroll
    for (int i = 0; i < 4; ++i) {
        int slot = i * 256 + t;
        int am = slot >> 3, ac = slot & 7;
        aoff[i] = (size_t)(m0 + am) * K + (size_t)((ac ^ (am & 7)) * 8);
    }
    // B staging (4 qwords per thread: col bn, krows bk0..bk0+3)
    const int bn  = t & 127;
    const int bk0 = (t >> 7) * 4;
    int bwoff[4];
#pragma unroll
    for (int j = 0; j < 4; ++j)
        bwoff[j] = (bn * 128 + (bk0 + j) * 16) ^ ((bn & 7) << 4);

    // wave col remap (RoPE partners intra-lane)
    int ncm[4];
#pragma unroll
    for (int nf = 0; nf < 4; ++nf)
        ncm[nf] = wc * 32 + (nf & 1) * 16 + lr + ((nf & 2) ? 64 : 0);

    const int xorA = (lr & 7) << 4;
    int aroff[4][2], broff[4][2];
#pragma unroll
    for (int mf = 0; mf < 4; ++mf)
#pragma unroll
        for (int ks = 0; ks < 2; ++ks)
            aroff[mf][ks] = (((wr * 64 + mf * 16 + lr) * 128) + lg * 16 + ks * 64) ^ xorA;
#pragma unroll
    for (int nf = 0; nf < 4; ++nf)
#pragma unroll
        for (int ks = 0; ks < 2; ++ks)
            broff[nf][ks] = ((ncm[nf] * 128) + lg * 16 + ks * 64) ^ xorA;

    f32x4 macc[4][4];
#pragma unroll
    for (int mf = 0; mf < 4; ++mf)
#pragma unroll
        for (int nf = 0; nf < 4; ++nf) macc[mf][nf] = f32x4{0.f, 0.f, 0.f, 0.f};
    uint qr[4];
    float scf, zf;

#define QKV_QW(tile) { int g8 = (tile) * 8; int gg = (tile) >> 1; \
    _Pragma("unroll") \
    for (int j = 0; j < 4; ++j) \
        qr[j] = (uint)QW[(size_t)(g8 + bk0 + j) * Nw + nbase + bn]; \
    scf = SC[(size_t)gg * Nw + nbase + bn]; \
    zf  = (float)QZ[(size_t)gg * Nw + nbase + bn]; }

#define QKV_STAGE_A(AH, k0) { \
    gl_lds16(Xf + (k0) + aoff[0], (char*)(AH) + ldsAw); \
    gl_lds16(Xf + (k0) + aoff[1], (char*)(AH) + 4096 + ldsAw); \
    gl_lds16(Xf + (k0) + aoff[2], (char*)(AH) + 8192 + ldsAw); \
    gl_lds16(Xf + (k0) + aoff[3], (char*)(AH) + 12288 + ldsAw); }

#define QKV_BWRITE(BT) { \
    ushort sch = f2h(scf); \
    float schf = h2f(sch); \
    ushort msc = f2h(-128.0f * schf);   /* exact exponent shift */ \
    ushort nzs = f2h(-(zf * schf)); \
    half2v S2 = {__builtin_bit_cast(_Float16, sch), __builtin_bit_cast(_Float16, sch)}; \
    half2v M2 = {__builtin_bit_cast(_Float16, msc), __builtin_bit_cast(_Float16, msc)}; \
    half2v Z2 = {__builtin_bit_cast(_Float16, nzs), __builtin_bit_cast(_Float16, nzs)}; \
    _Pragma("unroll") \
    for (int j = 0; j < 4; ++j) { \
        uint q = qr[j]; \
        uint b0 = q & 0xFFu, b1 = (q >> 8) & 0xFFu, b2 = (q >> 16) & 0xFFu, b3 = q >> 24; \
        uint e0 = 0x58005800u | ((b0 & 0xFu) << 3) | ((b0 & 0xF0u) << 15); \
        uint e1 = 0x58005800u | ((b1 & 0xFu) << 3) | ((b1 & 0xF0u) << 15); \
        uint e2 = 0x58005800u | ((b2 & 0xFu) << 3) | ((b2 & 0xF0u) << 15); \
        uint e3 = 0x58005800u | ((b3 & 0xFu) << 3) | ((b3 & 0xF0u) << 15); \
        half2v w0 = __builtin_bit_cast(half2v, e0) * S2 + M2; w0 = w0 + Z2; \
        half2v w1 = __builtin_bit_cast(half2v, e1) * S2 + M2; w1 = w1 + Z2; \
        half2v w2 = __builtin_bit_cast(half2v, e2) * S2 + M2; w2 = w2 + Z2; \
        half2v w3 = __builtin_bit_cast(half2v, e3) * S2 + M2; w3 = w3 + Z2; \
        uint4 dw = {__builtin_bit_cast(uint, w0), __builtin_bit_cast(uint, w1), \
                    __builtin_bit_cast(uint, w2), __builtin_bit_cast(uint, w3)}; \
        *(uint4*)((char*)(BT) + bwoff[j]) = dw; \
    } }

#define QKV_COMPUTE(AH, BT) { \
    _Pragma("unroll") \
    for (int ks = 0; ks < 2; ++ks) { \
        half8v av[4], bv[4]; \
        _Pragma("unroll") \
        for (int mf = 0; mf < 4; ++mf) \
            av[mf] = *(const half8v*)((const char*)(AH) + aroff[mf][ks]); \
        _Pragma("unroll") \
        for (int nf = 0; nf < 4; ++nf) \
            bv[nf] = *(const half8v*)((const char*)(BT) + broff[nf][ks]); \
        _Pragma("unroll") \
        for (int mf = 0; mf < 4; ++mf) \
            _Pragma("unroll") \
            for (int nf = 0; nf < 4; ++nf) \
                macc[mf][nf] = __builtin_amdgcn_mfma_f32_16x16x32_f16(av[mf], bv[nf], macc[mf][nf], 0, 0, 0); \
    } }

    // ---- prologue: tile 0 resident, QW(1) in flight ----
    QKV_QW(0);
    QKV_BWRITE(B0);               // compiler drains qr(0) (prologue only)
    QKV_STAGE_A(A0, 0);           // +4
    QKV_QW(1);                    // +6 -> 10
    WAIT_LGKM0;
    WAIT_VM(6);                   // retire STAGE_A(0)
    RAW_BARRIER;

    // ---- main loop: tiles 0..37 in pairs; invariant at tile entry:
    //      A/B[t&1] resident, QW(t+1) 6 loads in flight ----
    for (int g = 0; g < 19; ++g) {
        // tile 2g
        QKV_STAGE_A(A1, (2 * g + 1) * 64);   // +4 -> 10
        QKV_COMPUTE(A0, B0);
        QKV_BWRITE(B1);                      // auto vmcnt(4) for qr(2g+1)
        QKV_QW(2 * g + 2);                   // +6
        WAIT_LGKM0;
        WAIT_VM(6);                          // retire STAGE_A(2g+1)
        RAW_BARRIER;
        // tile 2g+1
        QKV_STAGE_A(A0, (2 * g + 2) * 64);
        QKV_COMPUTE(A1, B1);
        QKV_BWRITE(B0);
        QKV_QW(2 * g + 3);
        WAIT_LGKM0;
        WAIT_VM(6);
        RAW_BARRIER;
    }
    // ---- tail: tiles 38, 39 ----
    QKV_STAGE_A(A1, 39 * 64);
    QKV_COMPUTE(A0, B0);                     // tile 38
    QKV_BWRITE(B1);                          // qr(39)
    WAIT_LGKM0;
    WAIT_VM(0);                              // retire STAGE_A(39)
    RAW_BARRIER;
    QKV_COMPUTE(A1, B1);                     // tile 39

    // ---- +bias ----
#pragma unroll
    for (int nf = 0; nf < 4; ++nf) {
        float bv = BI[nbase + ncm[nf]];
#pragma unroll
        for (int mf = 0; mf < 4; ++mf)
#pragma unroll
            for (int r = 0; r < 4; ++r) macc[mf][nf][r] += bv;
    }

    // ---- epilogue ----
    if (region == 2) {
#pragma unroll
        for (int mf = 0; mf < 4; ++mf)
#pragma unroll
            for (int r = 0; r < 4; ++r) {
                int row = m0 + wr * 64 + mf * 16 + lg * 4 + r;
#pragma unroll
                for (int nf = 0; nf < 4; ++nf)
                    Vrm[(size_t)row * (NKV * HD) + nbase + ncm[nf]] = f2h(macc[mf][nf][r]);
            }
    } else {
        ushort* OF = (region == 0) ? Qf : Kf;
        const int No = (region == 0) ? NH * HD : NKV * HD;
        const float osc = (region == 0) ? 0.08838834764831845f : 1.0f;
#pragma unroll
        for (int mf = 0; mf < 4; ++mf)
#pragma unroll
            for (int r = 0; r < 4; ++r) {
                int row = m0 + wr * 64 + mf * 16 + lg * 4 + r;
                const float* cb = &cosb[(size_t)row * HD];
                const float* sb = &sinb[(size_t)row * HD];
#pragma unroll
                for (int nf = 0; nf < 2; ++nf) {
                    int d = wc * 32 + nf * 16 + lr;           // 0..63
                    float a = macc[mf][nf][r];
                    float b = macc[mf][nf + 2][r];
                    float o1 = (a * cb[d]      - b * sb[d])      * osc;
                    float o2 = (b * cb[d + 64] + a * sb[d + 64]) * osc;
                    OF[(size_t)row * No + nbase + d]      = f2h(o1);
                    OF[(size_t)row * No + nbase + d + 64] = f2h(o2);
                }
            }
    }
#undef QKV_QW
#undef QKV_STAGE_A
#undef QKV_BWRITE
#undef QKV_COMPUTE
}

// ---------------------------------------------------------------------------
// V transpose: Vrm [S][1024] fp16 -> VfT [1024][S]. 64x64 LDS tiles.
// ---------------------------------------------------------------------------
__global__ __launch_bounds__(256) void vtrans_kernel(
    const ushort* __restrict__ Vrm, ushort* __restrict__ VfT)
{
    __shared__ ushort Ts[64][65];
    const int s0 = blockIdx.x * 64;
    const int n0 = blockIdx.y * 64;
    const int t  = threadIdx.x;
    {
        int r = t >> 2, c0 = (t & 3) * 16;
        uint4 v0 = *(const uint4*)&Vrm[(size_t)(s0 + r) * (NKV * HD) + n0 + c0];
        uint4 v1 = *(const uint4*)&Vrm[(size_t)(s0 + r) * (NKV * HD) + n0 + c0 + 8];
        const ushort* pv = (const ushort*)&v0;
#pragma unroll
        for (int j = 0; j < 8; ++j) Ts[r][c0 + j] = pv[j];
        pv = (const ushort*)&v1;
#pragma unroll
        for (int j = 0; j < 8; ++j) Ts[r][c0 + 8 + j] = pv[j];
    }
    __syncthreads();
    {
        int rn = t >> 2, cs0 = (t & 3) * 16;
        ushort ob[16];
#pragma unroll
        for (int j = 0; j < 16; ++j) ob[j] = Ts[cs0 + j][rn];
        ushort* dst = &VfT[(size_t)(n0 + rn) * S_LEN + s0 + cs0];
        *(uint4*)dst = ((uint4*)ob)[0];
        *(uint4*)(dst + 8) = ((uint4*)ob)[1];
    }
}

// ===========================================================================
// O-projection, fp16 direct-scaled B, counted-vmcnt pipeline (same template).
// Block 128Mx128N, 4 waves (2Mx2N), wave tile 64x64. LDS 64 KB. 64 K-tiles.
// ===========================================================================
__global__ __launch_bounds__(256) void oproj6_kernel(
    const ushort* __restrict__ Xb, const int* __restrict__ QW,
    const float* __restrict__ SC, const int* __restrict__ QZ,
    float* __restrict__ Y)
{
    __shared__ __align__(16) char LDSB[65536];
    ushort* A0 = (ushort*)(LDSB);
    ushort* A1 = (ushort*)(LDSB + 16384);
    ushort* B0 = (ushort*)(LDSB + 32768);
    ushort* B1 = (ushort*)(LDSB + 49152);

    const int t  = threadIdx.x;
    const int w  = t >> 6;
    const int l  = t & 63;
    const int lg = l >> 4;
    const int lr = l & 15;
    const int wr = w >> 1;
    const int wc = w & 1;
    const int K  = NH * HD;      // 4096
    const int N  = HIDDEN;       // 2560

    const int bid = blockIdx.x;
    const int swz = (bid & 7) * 40 + (bid >> 3);   // 320 = 8*40
    const int n0  = (swz % 20) * 128;
    const int m0  = (swz / 20) * 128;

    const int ldsAw = w * 1024;
    size_t aoff[4];
#pragma unroll
    for (int i = 0; i < 4; ++i) {
        int slot = i * 256 + t;
        int am = slot >> 3, ac = slot & 7;
        aoff[i] = (size_t)(m0 + am) * K + (size_t)((ac ^ (am & 7)) * 8);
    }
    const int bn  = t & 127;
    const int bk0 = (t >> 7) * 4;
    int bwoff[4];
#pragma unroll
    for (int j = 0; j < 4; ++j)
        bwoff[j] = (bn * 128 + (bk0 + j) * 16) ^ ((bn & 7) << 4);

    const int xorA = (lr & 7) << 4;
    int aroff[4][2], broff[4][2];
#pragma unroll
    for (int mf = 0; mf < 4; ++mf)
#pragma unroll
        for (int ks = 0; ks < 2; ++ks)
            aroff[mf][ks] = (((wr * 64 + mf * 16 + lr) * 128) + lg * 16 + ks * 64) ^ xorA;
#pragma unroll
    for (int nf = 0; nf < 4; ++nf)
#pragma unroll
        for (int ks = 0; ks < 2; ++ks)
            broff[nf][ks] = (((wc * 64 + nf * 16 + lr) * 128) + lg * 16 + ks * 64) ^ xorA;

    f32x4 macc[4][4];
#pragma unroll
    for (int mf = 0; mf < 4; ++mf)
#pragma unroll
        for (int nf = 0; nf < 4; ++nf) macc[mf][nf] = f32x4{0.f, 0.f, 0.f, 0.f};
    uint qr[4];
    float scf, zf;

#define OP_QW(tile) { int g8 = (tile) * 8; int gg = (tile) >> 1; \
    _Pragma("unroll") \
    for (int j = 0; j < 4; ++j) \
        qr[j] = (uint)QW[(size_t)(g8 + bk0 + j) * N + n0 + bn]; \
    scf = SC[(size_t)gg * N + n0 + bn]; \
    zf  = (float)QZ[(size_t)gg * N + n0 + bn]; }

#define OP_STAGE_A(AH, k0) { \
    gl_lds16(Xb + (k0) + aoff[0], (char*)(AH) + ldsAw); \
    gl_lds16(Xb + (k0) + aoff[1], (char*)(AH) + 4096 + ldsAw); \
    gl_lds16(Xb + (k0) + aoff[2], (char*)(AH) + 8192 + ldsAw); \
    gl_lds16(Xb + (k0) + aoff[3], (char*)(AH) + 12288 + ldsAw); }

#define OP_BWRITE(BT) { \
    ushort sch = f2h(scf); \
    float schf = h2f(sch); \
    ushort msc = f2h(-128.0f * schf); \
    ushort nzs = f2h(-(zf * schf)); \
    half2v S2 = {__builtin_bit_cast(_Float16, sch), __builtin_bit_cast(_Float16, sch)}; \
    half2v M2 = {__builtin_bit_cast(_Float16, msc), __builtin_bit_cast(_Float16, msc)}; \
    half2v Z2 = {__builtin_bit_cast(_Float16, nzs), __builtin_bit_cast(_Float16, nzs)}; \
    _Pragma("unroll") \
    for (int j = 0; j < 4; ++j) { \
        uint q = qr[j]; \
        uint b0 = q & 0xFFu, b1 = (q >> 8) & 0xFFu, b2 = (q >> 16) & 0xFFu, b3 = q >> 24; \
        uint e0 = 0x58005800u | ((b0 & 0xFu) << 3) | ((b0 & 0xF0u) << 15); \
        uint e1 = 0x58005800u | ((b1 & 0xFu) << 3) | ((b1 & 0xF0u) << 15); \
        uint e2 = 0x58005800u | ((b2 & 0xFu) << 3) | ((b2 & 0xF0u) << 15); \
        uint e3 = 0x58005800u | ((b3 & 0xFu) << 3) | ((b3 & 0xF0u) << 15); \
        half2v w0 = __builtin_bit_cast(half2v, e0) * S2 + M2; w0 = w0 + Z2; \
        half2v w1 = __builtin_bit_cast(half2v, e1) * S2 + M2; w1 = w1 + Z2; \
        half2v w2 = __builtin_bit_cast(half2v, e2) * S2 + M2; w2 = w2 + Z2; \
        half2v w3 = __builtin_bit_cast(half2v, e3) * S2 + M2; w3 = w3 + Z2; \
        uint4 dw = {__builtin_bit_cast(uint, w0), __builtin_bit_cast(uint, w1), \
                    __builtin_bit_cast(uint, w2), __builtin_bit_cast(uint, w3)}; \
        *(uint4*)((char*)(BT) + bwoff[j]) = dw; \
    } }

#define OP_COMPUTE(AH, BT) { \
    _Pragma("unroll") \
    for (int ks = 0; ks < 2; ++ks) { \
        half8v av[4], bv[4]; \
        _Pragma("unroll") \
        for (int mf = 0; mf < 4; ++mf) \
            av[mf] = *(const half8v*)((const char*)(AH) + aroff[mf][ks]); \
        _Pragma("unroll") \
        for (int nf = 0; nf < 4; ++nf) \
            bv[nf] = *(const half8v*)((const char*)(BT) + broff[nf][ks]); \
        _Pragma("unroll") \
        for (int mf = 0; mf < 4; ++mf) \
            _Pragma("unroll") \
            for (int nf = 0; nf < 4; ++nf) \
                macc[mf][nf] = __builtin_amdgcn_mfma_f32_16x16x32_f16(av[mf], bv[nf], macc[mf][nf], 0, 0, 0); \
    } }

    // prologue
    OP_QW(0);
    OP_BWRITE(B0);
    OP_STAGE_A(A0, 0);
    OP_QW(1);
    WAIT_LGKM0;
    WAIT_VM(6);
    RAW_BARRIER;

    // tiles 0..61 in pairs
    for (int g = 0; g < 31; ++g) {
        OP_STAGE_A(A1, (2 * g + 1) * 64);
        OP_COMPUTE(A0, B0);
        OP_BWRITE(B1);
        OP_QW(2 * g + 2);
        WAIT_LGKM0;
        WAIT_VM(6);
        RAW_BARRIER;
        OP_STAGE_A(A0, (2 * g + 2) * 64);
        OP_COMPUTE(A1, B1);
        OP_BWRITE(B0);
        OP_QW(2 * g + 3);
        WAIT_LGKM0;
        WAIT_VM(6);
        RAW_BARRIER;
    }
    // tail: tiles 62, 63
    OP_STAGE_A(A1, 63 * 64);
    OP_COMPUTE(A0, B0);
    OP_BWRITE(B1);
    WAIT_LGKM0;
    WAIT_VM(0);
    RAW_BARRIER;
    OP_COMPUTE(A1, B1);

#pragma unroll
    for (int mf = 0; mf < 4; ++mf)
#pragma unroll
        for (int r = 0; r < 4; ++r) {
            int row = m0 + wr * 64 + mf * 16 + lg * 4 + r;
#pragma unroll
            for (int nf = 0; nf < 4; ++nf)
                Y[(size_t)row * N + n0 + wc * 64 + nf * 16 + lr] = macc[mf][nf][r];
        }
#undef OP_QW
#undef OP_STAGE_A
#undef OP_BWRITE
#undef OP_COMPUTE
}

// ---------------------------------------------------------------------------
// Causal GQA flash attention, fp16 MFMA, swapped operands (unchanged r11).
// ---------------------------------------------------------------------------
__global__ __launch_bounds__(256) void attn_mfma_kernel(
    const ushort* __restrict__ Qh,   // [S][NH*HD] fp16, roped, *1/sqrt(HD)
    const ushort* __restrict__ Kh,   // [S][NKV*HD] fp16, roped
    const ushort* __restrict__ Vt,   // [NKV*HD][S] fp16 (transposed)
    ushort* __restrict__ AO)         // [S][NH*HD] fp16
{
    __shared__ ushort KsF[32 * 128];           // 8 KB, swz ^((row&7)<<4)
    __shared__ ushort Vs[128 * 32];            // 8 KB, swz ^((dim&3)<<4)
    __shared__ __align__(16) char PsB[4 * 1280];  // P: 16 rows x 80B per wave

    const int h  = blockIdx.x;
    const int qb = gridDim.y - 1 - blockIdx.y;
    const int s0 = qb * 64;
    const int t  = threadIdx.x;
    const int w  = t >> 6;
    const int l  = t & 63;
    const int lg = l >> 4;
    const int lr = l & 15;
    const int kvh = h >> 2;
    const int qw = s0 + w * 16;
    const int q  = qw + lr;          // this lane's q-row

    half8v qf[4];
#pragma unroll
    for (int d = 0; d < 4; ++d) {
        size_t off = (size_t)q * (NH * HD) + h * HD + d * 32 + lg * 8;
        qf[d] = *(const half8v*)&Qh[off];
    }

    f32x4 o[8];
#pragma unroll
    for (int i = 0; i < 8; ++i) o[i] = f32x4{0.f, 0.f, 0.f, 0.f};
    float m = -1e30f, lsum = 0.f;
    char* pw = PsB + w * 1280;

    const int ntiles = qb * 2 + 2;
    for (int kt = 0; kt < ntiles; ++kt) {
        const int k0 = kt * 32;
#pragma unroll
        for (int i = 0; i < 2; ++i) {
            int slot = w * 128 + i * 64 + l;
            int mr = slot >> 4, c = slot & 15;
            size_t goff = (size_t)(k0 + mr) * (NKV * HD) + kvh * HD + ((c ^ (mr & 7)) * 8);
            gl_lds16(Kh + goff, (char*)KsF + (w * 128 + i * 64) * 16);
        }
#pragma unroll
        for (int i = 0; i < 2; ++i) {
            int slot = w * 128 + i * 64 + l;
            int dim = slot >> 2, c = slot & 3;
            size_t goff = (size_t)(kvh * HD + dim) * S_LEN + k0 + ((c ^ (dim & 3)) * 8);
            gl_lds16(Vt + goff, (char*)Vs + (w * 128 + i * 64) * 16);
        }
        __syncthreads();

        if (k0 <= qw + 15) {   // wave-uniform causal skip
            f32x4 s[2];
            s[0] = f32x4{0.f, 0.f, 0.f, 0.f};
            s[1] = f32x4{0.f, 0.f, 0.f, 0.f};
#pragma unroll
            for (int d = 0; d < 4; ++d) {
#pragma unroll
                for (int nt2 = 0; nt2 < 2; ++nt2) {
                    int row = nt2 * 16 + lr;
                    int off = row * 256 + ((d * 64 + lg * 16) ^ ((row & 7) << 4));
                    half8v kf = *(const half8v*)((char*)KsF + off);
                    s[nt2] = __builtin_amdgcn_mfma_f32_16x16x32_f16(kf, qf[d], s[nt2], 0, 0, 0);
                }
            }
            float sv[8];
#pragma unroll
            for (int nt2 = 0; nt2 < 2; ++nt2)
#pragma unroll
                for (int r = 0; r < 4; ++r) {
                    int kv = k0 + nt2 * 16 + lg * 4 + r;
                    sv[nt2 * 4 + r] = (kv <= q) ? s[nt2][r] : -1e30f;
                }
            float mx = sv[0];
#pragma unroll
            for (int j = 1; j < 8; ++j) mx = fmaxf(mx, sv[j]);
            mx = fmaxf(mx, __shfl_xor(mx, 16));
            mx = fmaxf(mx, __shfl_xor(mx, 32));
            float mnew = fmaxf(m, mx);
            float resc = __expf(m - mnew);
            m = mnew;
            float p[8], ps = 0.f;
#pragma unroll
            for (int j = 0; j < 8; ++j) { p[j] = __expf(sv[j] - mnew); ps += p[j]; }
            ps += __shfl_xor(ps, 16);
            ps += __shfl_xor(ps, 32);
            lsum = lsum * resc + ps;
#pragma unroll
            for (int dt = 0; dt < 8; ++dt)
#pragma unroll
                for (int r = 0; r < 4; ++r) o[dt][r] *= resc;
            uint2 w0 = {pk2(f2h(p[0]), f2h(p[1])), pk2(f2h(p[2]), f2h(p[3]))};
            uint2 w1 = {pk2(f2h(p[4]), f2h(p[5])), pk2(f2h(p[6]), f2h(p[7]))};
            *(uint2*)(pw + lr * 80 + lg * 8)      = w0;
            *(uint2*)(pw + lr * 80 + 32 + lg * 8) = w1;
            asm volatile("s_waitcnt lgkmcnt(0)" ::: "memory");
            half8v pf = *(const half8v*)(pw + lr * 80 + lg * 16);
#pragma unroll
            for (int dt = 0; dt < 8; ++dt) {
                int dim = dt * 16 + lr;
                half8v vf = *(const half8v*)((char*)Vs + dim * 64 + ((lg * 16) ^ ((dim & 3) << 4)));
                o[dt] = __builtin_amdgcn_mfma_f32_16x16x32_f16(vf, pf, o[dt], 0, 0, 0);
            }
        }
        __syncthreads();
    }

    float inv = 1.f / lsum;
    ushort* dst = &AO[(size_t)q * (NH * HD) + h * HD];
#pragma unroll
    for (int dt = 0; dt < 8; ++dt) {
        uint2 ov = {pk2(f2h(o[dt][0] * inv), f2h(o[dt][1] * inv)),
                    pk2(f2h(o[dt][2] * inv), f2h(o[dt][3] * inv))};
        *(uint2*)(dst + dt * 16 + lg * 4) = ov;
    }
}

// ---------------------------------------------------------------------------
extern "C" void kernel_launch(void* const* d_in, const int* in_sizes, int n_in,
                              void* d_out, int out_size, void* d_ws, size_t ws_size,
                              hipStream_t stream)
{
    const float* x    = (const float*)d_in[0];
    const float* cosb = (const float*)d_in[1];
    const float* sinb = (const float*)d_in[2];
    const float* q_sc = (const float*)d_in[3];
    const float* q_b  = (const float*)d_in[4];
    const float* k_sc = (const float*)d_in[5];
    const float* k_b  = (const float*)d_in[6];
    const float* v_sc = (const float*)d_in[7];
    const float* v_b  = (const float*)d_in[8];
    const float* o_sc = (const float*)d_in[9];
    const int* q_qw   = (const int*)d_in[10];
    const int* q_qz   = (const int*)d_in[11];
    const int* k_qw   = (const int*)d_in[12];
    const int* k_qz   = (const int*)d_in[13];
    const int* v_qw   = (const int*)d_in[14];
    const int* v_qz   = (const int*)d_in[15];
    const int* o_qw   = (const int*)d_in[16];
    const int* o_qz   = (const int*)d_in[17];
    float* out = (float*)d_out;

    // ws layout (MB):
    //   0:  Xf16 (10)  [aliased by AOf16 (16) after qkv7]
    //   16: Qf (16) | 32: Kf (4) | 36: Vrm (4) | 40: VfT (4)
    char* ws = (char*)d_ws;
    ushort* Xf   = (ushort*)ws;
    ushort* AOf  = (ushort*)ws;                                  // alias
    ushort* Qf   = (ushort*)(ws + (size_t)16 * 1024 * 1024);
    ushort* Kf   = (ushort*)(ws + (size_t)32 * 1024 * 1024);
    ushort* Vrm  = (ushort*)(ws + (size_t)36 * 1024 * 1024);
    ushort* VfT  = (ushort*)(ws + (size_t)40 * 1024 * 1024);

    xcvt_kernel<<<S_LEN, 320, 0, stream>>>(x, Xf);

    qkv7_kernel<<<768, 256, 0, stream>>>(
        Xf,
        q_qw, q_sc, q_qz, q_b,
        k_qw, k_sc, k_qz, k_b,
        v_qw, v_sc, v_qz, v_b,
        cosb, sinb, Qf, Kf, Vrm);

    vtrans_kernel<<<dim3(S_LEN / 64, (NKV * HD) / 64), 256, 0, stream>>>(Vrm, VfT);

    attn_mfma_kernel<<<dim3(NH, S_LEN / 64), 256, 0, stream>>>(Qf, Kf, VfT, AOf);

    oproj6_kernel<<<320, 256, 0, stream>>>(
        AOf, o_qw, o_sc, o_qz, out);
}

// Round 13
// 264.545 us; speedup vs baseline: 1.0857x; 1.0040x over previous
//
#include <hip/hip_runtime.h>
#include <hip/hip_bf16.h>
#include <cstdint>

#define S_LEN 2048
#define HIDDEN 2560
#define NH 32
#define NKV 8
#define HD 128
#define GS 128

typedef __attribute__((ext_vector_type(8))) _Float16 half8v;    // 8 x fp16
typedef __attribute__((ext_vector_type(2))) _Float16 half2v;    // 2 x fp16
typedef __attribute__((ext_vector_type(4))) float f32x4;
typedef unsigned int uint;
typedef unsigned short ushort;

__device__ inline ushort f2h(float f) {
    _Float16 h = (_Float16)f;
    return __builtin_bit_cast(ushort, h);
}
__device__ inline float h2f(ushort u) {
    return (float)__builtin_bit_cast(_Float16, u);
}
__device__ inline uint pk2(ushort a, ushort b) { return (uint)a | ((uint)b << 16); }

// async global->LDS, 16B per lane; lds base must be wave-uniform
__device__ __attribute__((always_inline)) inline void gl_lds16(const void* g, void* l) {
    __builtin_amdgcn_global_load_lds(
        (const __attribute__((address_space(1))) unsigned int*)g,
        (__attribute__((address_space(3))) unsigned int*)l, 16, 0, 0);
}

// counted-waitcnt barrier helpers (T3+T4): raw s_barrier, no vmcnt(0) drain
#define WAIT_LGKM0  asm volatile("s_waitcnt lgkmcnt(0)" ::: "memory")
#define WAIT_VM(N)  asm volatile("s_waitcnt vmcnt(" #N ")" ::: "memory")
#define RAW_BARRIER { __builtin_amdgcn_s_barrier(); __builtin_amdgcn_sched_barrier(0); }

// ---------------------------------------------------------------------------
// X -> fp16. One block per row, 320 thr x 8 els.
// ---------------------------------------------------------------------------
__global__ __launch_bounds__(320) void xcvt_kernel(
    const float* __restrict__ X, ushort* __restrict__ Xf)
{
    const int row = blockIdx.x;
    const int t   = threadIdx.x;
    const size_t base = (size_t)row * HIDDEN + t * 8;
    float4 a = *(const float4*)&X[base];
    float4 b = *(const float4*)&X[base + 4];
    uint4 hw = {pk2(f2h(a.x), f2h(a.y)), pk2(f2h(a.z), f2h(a.w)),
                pk2(f2h(b.x), f2h(b.y)), pk2(f2h(b.z), f2h(b.w))};
    *(uint4*)&Xf[base] = hw;
}

// ===========================================================================
// Fused Q/K/V AWQ-int4 MFMA GEMM, fp16 direct-scaled B, counted-vmcnt
// pipeline (unchanged round 12; 613 TF = 2-phase structural ceiling).
// ===========================================================================
__global__ __launch_bounds__(256) void qkv7_kernel(
    const ushort* __restrict__ Xf,
    const int* __restrict__ q_qw, const float* __restrict__ q_sc,
    const int* __restrict__ q_qz, const float* __restrict__ q_b,
    const int* __restrict__ k_qw, const float* __restrict__ k_sc,
    const int* __restrict__ k_qz, const float* __restrict__ k_b,
    const int* __restrict__ v_qw, const float* __restrict__ v_sc,
    const int* __restrict__ v_qz, const float* __restrict__ v_b,
    const float* __restrict__ cosb, const float* __restrict__ sinb,
    ushort* __restrict__ Qf, ushort* __restrict__ Kf,
    ushort* __restrict__ Vrm)
{
    __shared__ __align__(16) char LDSB[65536];
    ushort* A0 = (ushort*)(LDSB);
    ushort* A1 = (ushort*)(LDSB + 16384);
    ushort* B0 = (ushort*)(LDSB + 32768);
    ushort* B1 = (ushort*)(LDSB + 49152);

    const int t  = threadIdx.x;
    const int w  = t >> 6;        // 0..3
    const int l  = t & 63;
    const int lg = l >> 4;
    const int lr = l & 15;
    const int wr = w >> 1;        // M half
    const int wc = w & 1;         // N half
    const int K  = HIDDEN;

    const int bid = blockIdx.x;
    const int swz = (bid & 7) * 96 + (bid >> 3);
    const int nblk = swz % 48;
    const int m0   = (swz / 48) * 128;

    int region, nbase, Nw;
    const int* QW; const float* SC; const int* QZ; const float* BI;
    if (nblk < 32)      { region = 0; nbase = nblk * 128;        Nw = NH * HD;
                          QW = q_qw; SC = q_sc; QZ = q_qz; BI = q_b; }
    else if (nblk < 40) { region = 1; nbase = (nblk - 32) * 128; Nw = NKV * HD;
                          QW = k_qw; SC = k_sc; QZ = k_qz; BI = k_b; }
    else                { region = 2; nbase = (nblk - 40) * 128; Nw = NKV * HD;
                          QW = v_qw; SC = v_sc; QZ = v_qz; BI = v_b; }

    const int ldsAw = w * 1024;
    size_t aoff[4];
#pragma unroll
    for (int i = 0; i < 4; ++i) {
        int slot = i * 256 + t;
        int am = slot >> 3, ac = slot & 7;
        aoff[i] = (size_t)(m0 + am) * K + (size_t)((ac ^ (am & 7)) * 8);
    }
    const int bn  = t & 127;
    const int bk0 = (t >> 7) * 4;
    int bwoff[4];
#pragma unroll
    for (int j = 0; j < 4; ++j)
        bwoff[j] = (bn * 128 + (bk0 + j) * 16) ^ ((bn & 7) << 4);

    int ncm[4];
#pragma unroll
    for (int nf = 0; nf < 4; ++nf)
        ncm[nf] = wc * 32 + (nf & 1) * 16 + lr + ((nf & 2) ? 64 : 0);

    const int xorA = (lr & 7) << 4;
    int aroff[4][2], broff[4][2];
#pragma unroll
    for (int mf = 0; mf < 4; ++mf)
#pragma unroll
        for (int ks = 0; ks < 2; ++ks)
            aroff[mf][ks] = (((wr * 64 + mf * 16 + lr) * 128) + lg * 16 + ks * 64) ^ xorA;
#pragma unroll
    for (int nf = 0; nf < 4; ++nf)
#pragma unroll
        for (int ks = 0; ks < 2; ++ks)
            broff[nf][ks] = ((ncm[nf] * 128) + lg * 16 + ks * 64) ^ xorA;

    f32x4 macc[4][4];
#pragma unroll
    for (int mf = 0; mf < 4; ++mf)
#pragma unroll
        for (int nf = 0; nf < 4; ++nf) macc[mf][nf] = f32x4{0.f, 0.f, 0.f, 0.f};
    uint qr[4];
    float scf, zf;

#define QKV_QW(tile) { int g8 = (tile) * 8; int gg = (tile) >> 1; \
    _Pragma("unroll") \
    for (int j = 0; j < 4; ++j) \
        qr[j] = (uint)QW[(size_t)(g8 + bk0 + j) * Nw + nbase + bn]; \
    scf = SC[(size_t)gg * Nw + nbase + bn]; \
    zf  = (float)QZ[(size_t)gg * Nw + nbase + bn]; }

#define QKV_STAGE_A(AH, k0) { \
    gl_lds16(Xf + (k0) + aoff[0], (char*)(AH) + ldsAw); \
    gl_lds16(Xf + (k0) + aoff[1], (char*)(AH) + 4096 + ldsAw); \
    gl_lds16(Xf + (k0) + aoff[2], (char*)(AH) + 8192 + ldsAw); \
    gl_lds16(Xf + (k0) + aoff[3], (char*)(AH) + 12288 + ldsAw); }

#define QKV_BWRITE(BT) { \
    ushort sch = f2h(scf); \
    float schf = h2f(sch); \
    ushort msc = f2h(-128.0f * schf);   /* exact exponent shift */ \
    ushort nzs = f2h(-(zf * schf)); \
    half2v S2 = {__builtin_bit_cast(_Float16, sch), __builtin_bit_cast(_Float16, sch)}; \
    half2v M2 = {__builtin_bit_cast(_Float16, msc), __builtin_bit_cast(_Float16, msc)}; \
    half2v Z2 = {__builtin_bit_cast(_Float16, nzs), __builtin_bit_cast(_Float16, nzs)}; \
    _Pragma("unroll") \
    for (int j = 0; j < 4; ++j) { \
        uint q = qr[j]; \
        uint b0 = q & 0xFFu, b1 = (q >> 8) & 0xFFu, b2 = (q >> 16) & 0xFFu, b3 = q >> 24; \
        uint e0 = 0x58005800u | ((b0 & 0xFu) << 3) | ((b0 & 0xF0u) << 15); \
        uint e1 = 0x58005800u | ((b1 & 0xFu) << 3) | ((b1 & 0xF0u) << 15); \
        uint e2 = 0x58005800u | ((b2 & 0xFu) << 3) | ((b2 & 0xF0u) << 15); \
        uint e3 = 0x58005800u | ((b3 & 0xFu) << 3) | ((b3 & 0xF0u) << 15); \
        half2v w0 = __builtin_bit_cast(half2v, e0) * S2 + M2; w0 = w0 + Z2; \
        half2v w1 = __builtin_bit_cast(half2v, e1) * S2 + M2; w1 = w1 + Z2; \
        half2v w2 = __builtin_bit_cast(half2v, e2) * S2 + M2; w2 = w2 + Z2; \
        half2v w3 = __builtin_bit_cast(half2v, e3) * S2 + M2; w3 = w3 + Z2; \
        uint4 dw = {__builtin_bit_cast(uint, w0), __builtin_bit_cast(uint, w1), \
                    __builtin_bit_cast(uint, w2), __builtin_bit_cast(uint, w3)}; \
        *(uint4*)((char*)(BT) + bwoff[j]) = dw; \
    } }

#define QKV_COMPUTE(AH, BT) { \
    _Pragma("unroll") \
    for (int ks = 0; ks < 2; ++ks) { \
        half8v av[4], bv[4]; \
        _Pragma("unroll") \
        for (int mf = 0; mf < 4; ++mf) \
            av[mf] = *(const half8v*)((const char*)(AH) + aroff[mf][ks]); \
        _Pragma("unroll") \
        for (int nf = 0; nf < 4; ++nf) \
            bv[nf] = *(const half8v*)((const char*)(BT) + broff[nf][ks]); \
        _Pragma("unroll") \
        for (int mf = 0; mf < 4; ++mf) \
            _Pragma("unroll") \
            for (int nf = 0; nf < 4; ++nf) \
                macc[mf][nf] = __builtin_amdgcn_mfma_f32_16x16x32_f16(av[mf], bv[nf], macc[mf][nf], 0, 0, 0); \
    } }

    QKV_QW(0);
    QKV_BWRITE(B0);
    QKV_STAGE_A(A0, 0);
    QKV_QW(1);
    WAIT_LGKM0;
    WAIT_VM(6);
    RAW_BARRIER;

    for (int g = 0; g < 19; ++g) {
        QKV_STAGE_A(A1, (2 * g + 1) * 64);
        QKV_COMPUTE(A0, B0);
        QKV_BWRITE(B1);
        QKV_QW(2 * g + 2);
        WAIT_LGKM0;
        WAIT_VM(6);
        RAW_BARRIER;
        QKV_STAGE_A(A0, (2 * g + 2) * 64);
        QKV_COMPUTE(A1, B1);
        QKV_BWRITE(B0);
        QKV_QW(2 * g + 3);
        WAIT_LGKM0;
        WAIT_VM(6);
        RAW_BARRIER;
    }
    QKV_STAGE_A(A1, 39 * 64);
    QKV_COMPUTE(A0, B0);
    QKV_BWRITE(B1);
    WAIT_LGKM0;
    WAIT_VM(0);
    RAW_BARRIER;
    QKV_COMPUTE(A1, B1);

#pragma unroll
    for (int nf = 0; nf < 4; ++nf) {
        float bv = BI[nbase + ncm[nf]];
#pragma unroll
        for (int mf = 0; mf < 4; ++mf)
#pragma unroll
            for (int r = 0; r < 4; ++r) macc[mf][nf][r] += bv;
    }

    if (region == 2) {
#pragma unroll
        for (int mf = 0; mf < 4; ++mf)
#pragma unroll
            for (int r = 0; r < 4; ++r) {
                int row = m0 + wr * 64 + mf * 16 + lg * 4 + r;
#pragma unroll
                for (int nf = 0; nf < 4; ++nf)
                    Vrm[(size_t)row * (NKV * HD) + nbase + ncm[nf]] = f2h(macc[mf][nf][r]);
            }
    } else {
        ushort* OF = (region == 0) ? Qf : Kf;
        const int No = (region == 0) ? NH * HD : NKV * HD;
        const float osc = (region == 0) ? 0.08838834764831845f : 1.0f;
#pragma unroll
        for (int mf = 0; mf < 4; ++mf)
#pragma unroll
            for (int r = 0; r < 4; ++r) {
                int row = m0 + wr * 64 + mf * 16 + lg * 4 + r;
                const float* cb = &cosb[(size_t)row * HD];
                const float* sb = &sinb[(size_t)row * HD];
#pragma unroll
                for (int nf = 0; nf < 2; ++nf) {
                    int d = wc * 32 + nf * 16 + lr;           // 0..63
                    float a = macc[mf][nf][r];
                    float b = macc[mf][nf + 2][r];
                    float o1 = (a * cb[d]      - b * sb[d])      * osc;
                    float o2 = (b * cb[d + 64] + a * sb[d + 64]) * osc;
                    OF[(size_t)row * No + nbase + d]      = f2h(o1);
                    OF[(size_t)row * No + nbase + d + 64] = f2h(o2);
                }
            }
    }
#undef QKV_QW
#undef QKV_STAGE_A
#undef QKV_BWRITE
#undef QKV_COMPUTE
}

// ---------------------------------------------------------------------------
// V transpose: Vrm [S][1024] fp16 -> VfT [1024][S]. 64x64 LDS tiles.
// ---------------------------------------------------------------------------
__global__ __launch_bounds__(256) void vtrans_kernel(
    const ushort* __restrict__ Vrm, ushort* __restrict__ VfT)
{
    __shared__ ushort Ts[64][65];
    const int s0 = blockIdx.x * 64;
    const int n0 = blockIdx.y * 64;
    const int t  = threadIdx.x;
    {
        int r = t >> 2, c0 = (t & 3) * 16;
        uint4 v0 = *(const uint4*)&Vrm[(size_t)(s0 + r) * (NKV * HD) + n0 + c0];
        uint4 v1 = *(const uint4*)&Vrm[(size_t)(s0 + r) * (NKV * HD) + n0 + c0 + 8];
        const ushort* pv = (const ushort*)&v0;
#pragma unroll
        for (int j = 0; j < 8; ++j) Ts[r][c0 + j] = pv[j];
        pv = (const ushort*)&v1;
#pragma unroll
        for (int j = 0; j < 8; ++j) Ts[r][c0 + 8 + j] = pv[j];
    }
    __syncthreads();
    {
        int rn = t >> 2, cs0 = (t & 3) * 16;
        ushort ob[16];
#pragma unroll
        for (int j = 0; j < 16; ++j) ob[j] = Ts[cs0 + j][rn];
        ushort* dst = &VfT[(size_t)(n0 + rn) * S_LEN + s0 + cs0];
        *(uint4*)dst = ((uint4*)ob)[0];
        *(uint4*)(dst + 8) = ((uint4*)ob)[1];
    }
}

// ===========================================================================
// O-projection, fp16 direct-scaled B, counted-vmcnt (unchanged round 12).
// ===========================================================================
__global__ __launch_bounds__(256) void oproj6_kernel(
    const ushort* __restrict__ Xb, const int* __restrict__ QW,
    const float* __restrict__ SC, const int* __restrict__ QZ,
    float* __restrict__ Y)
{
    __shared__ __align__(16) char LDSB[65536];
    ushort* A0 = (ushort*)(LDSB);
    ushort* A1 = (ushort*)(LDSB + 16384);
    ushort* B0 = (ushort*)(LDSB + 32768);
    ushort* B1 = (ushort*)(LDSB + 49152);

    const int t  = threadIdx.x;
    const int w  = t >> 6;
    const int l  = t & 63;
    const int lg = l >> 4;
    const int lr = l & 15;
    const int wr = w >> 1;
    const int wc = w & 1;
    const int K  = NH * HD;      // 4096
    const int N  = HIDDEN;       // 2560

    const int bid = blockIdx.x;
    const int swz = (bid & 7) * 40 + (bid >> 3);   // 320 = 8*40
    const int n0  = (swz % 20) * 128;
    const int m0  = (swz / 20) * 128;

    const int ldsAw = w * 1024;
    size_t aoff[4];
#pragma unroll
    for (int i = 0; i < 4; ++i) {
        int slot = i * 256 + t;
        int am = slot >> 3, ac = slot & 7;
        aoff[i] = (size_t)(m0 + am) * K + (size_t)((ac ^ (am & 7)) * 8);
    }
    const int bn  = t & 127;
    const int bk0 = (t >> 7) * 4;
    int bwoff[4];
#pragma unroll
    for (int j = 0; j < 4; ++j)
        bwoff[j] = (bn * 128 + (bk0 + j) * 16) ^ ((bn & 7) << 4);

    const int xorA = (lr & 7) << 4;
    int aroff[4][2], broff[4][2];
#pragma unroll
    for (int mf = 0; mf < 4; ++mf)
#pragma unroll
        for (int ks = 0; ks < 2; ++ks)
            aroff[mf][ks] = (((wr * 64 + mf * 16 + lr) * 128) + lg * 16 + ks * 64) ^ xorA;
#pragma unroll
    for (int nf = 0; nf < 4; ++nf)
#pragma unroll
        for (int ks = 0; ks < 2; ++ks)
            broff[nf][ks] = (((wc * 64 + nf * 16 + lr) * 128) + lg * 16 + ks * 64) ^ xorA;

    f32x4 macc[4][4];
#pragma unroll
    for (int mf = 0; mf < 4; ++mf)
#pragma unroll
        for (int nf = 0; nf < 4; ++nf) macc[mf][nf] = f32x4{0.f, 0.f, 0.f, 0.f};
    uint qr[4];
    float scf, zf;

#define OP_QW(tile) { int g8 = (tile) * 8; int gg = (tile) >> 1; \
    _Pragma("unroll") \
    for (int j = 0; j < 4; ++j) \
        qr[j] = (uint)QW[(size_t)(g8 + bk0 + j) * N + n0 + bn]; \
    scf = SC[(size_t)gg * N + n0 + bn]; \
    zf  = (float)QZ[(size_t)gg * N + n0 + bn]; }

#define OP_STAGE_A(AH, k0) { \
    gl_lds16(Xb + (k0) + aoff[0], (char*)(AH) + ldsAw); \
    gl_lds16(Xb + (k0) + aoff[1], (char*)(AH) + 4096 + ldsAw); \
    gl_lds16(Xb + (k0) + aoff[2], (char*)(AH) + 8192 + ldsAw); \
    gl_lds16(Xb + (k0) + aoff[3], (char*)(AH) + 12288 + ldsAw); }

#define OP_BWRITE(BT) { \
    ushort sch = f2h(scf); \
    float schf = h2f(sch); \
    ushort msc = f2h(-128.0f * schf); \
    ushort nzs = f2h(-(zf * schf)); \
    half2v S2 = {__builtin_bit_cast(_Float16, sch), __builtin_bit_cast(_Float16, sch)}; \
    half2v M2 = {__builtin_bit_cast(_Float16, msc), __builtin_bit_cast(_Float16, msc)}; \
    half2v Z2 = {__builtin_bit_cast(_Float16, nzs), __builtin_bit_cast(_Float16, nzs)}; \
    _Pragma("unroll") \
    for (int j = 0; j < 4; ++j) { \
        uint q = qr[j]; \
        uint b0 = q & 0xFFu, b1 = (q >> 8) & 0xFFu, b2 = (q >> 16) & 0xFFu, b3 = q >> 24; \
        uint e0 = 0x58005800u | ((b0 & 0xFu) << 3) | ((b0 & 0xF0u) << 15); \
        uint e1 = 0x58005800u | ((b1 & 0xFu) << 3) | ((b1 & 0xF0u) << 15); \
        uint e2 = 0x58005800u | ((b2 & 0xFu) << 3) | ((b2 & 0xF0u) << 15); \
        uint e3 = 0x58005800u | ((b3 & 0xFu) << 3) | ((b3 & 0xF0u) << 15); \
        half2v w0 = __builtin_bit_cast(half2v, e0) * S2 + M2; w0 = w0 + Z2; \
        half2v w1 = __builtin_bit_cast(half2v, e1) * S2 + M2; w1 = w1 + Z2; \
        half2v w2 = __builtin_bit_cast(half2v, e2) * S2 + M2; w2 = w2 + Z2; \
        half2v w3 = __builtin_bit_cast(half2v, e3) * S2 + M2; w3 = w3 + Z2; \
        uint4 dw = {__builtin_bit_cast(uint, w0), __builtin_bit_cast(uint, w1), \
                    __builtin_bit_cast(uint, w2), __builtin_bit_cast(uint, w3)}; \
        *(uint4*)((char*)(BT) + bwoff[j]) = dw; \
    } }

#define OP_COMPUTE(AH, BT) { \
    _Pragma("unroll") \
    for (int ks = 0; ks < 2; ++ks) { \
        half8v av[4], bv[4]; \
        _Pragma("unroll") \
        for (int mf = 0; mf < 4; ++mf) \
            av[mf] = *(const half8v*)((const char*)(AH) + aroff[mf][ks]); \
        _Pragma("unroll") \
        for (int nf = 0; nf < 4; ++nf) \
            bv[nf] = *(const half8v*)((const char*)(BT) + broff[nf][ks]); \
        _Pragma("unroll") \
        for (int mf = 0; mf < 4; ++mf) \
            _Pragma("unroll") \
            for (int nf = 0; nf < 4; ++nf) \
                macc[mf][nf] = __builtin_amdgcn_mfma_f32_16x16x32_f16(av[mf], bv[nf], macc[mf][nf], 0, 0, 0); \
    } }

    OP_QW(0);
    OP_BWRITE(B0);
    OP_STAGE_A(A0, 0);
    OP_QW(1);
    WAIT_LGKM0;
    WAIT_VM(6);
    RAW_BARRIER;

    for (int g = 0; g < 31; ++g) {
        OP_STAGE_A(A1, (2 * g + 1) * 64);
        OP_COMPUTE(A0, B0);
        OP_BWRITE(B1);
        OP_QW(2 * g + 2);
        WAIT_LGKM0;
        WAIT_VM(6);
        RAW_BARRIER;
        OP_STAGE_A(A0, (2 * g + 2) * 64);
        OP_COMPUTE(A1, B1);
        OP_BWRITE(B0);
        OP_QW(2 * g + 3);
        WAIT_LGKM0;
        WAIT_VM(6);
        RAW_BARRIER;
    }
    OP_STAGE_A(A1, 63 * 64);
    OP_COMPUTE(A0, B0);
    OP_BWRITE(B1);
    WAIT_LGKM0;
    WAIT_VM(0);
    RAW_BARRIER;
    OP_COMPUTE(A1, B1);

#pragma unroll
    for (int mf = 0; mf < 4; ++mf)
#pragma unroll
        for (int r = 0; r < 4; ++r) {
            int row = m0 + wr * 64 + mf * 16 + lg * 4 + r;
#pragma unroll
            for (int nf = 0; nf < 4; ++nf)
                Y[(size_t)row * N + n0 + wc * 64 + nf * 16 + lr] = macc[mf][nf][r];
        }
#undef OP_QW
#undef OP_STAGE_A
#undef OP_BWRITE
#undef OP_COMPUTE
}

// ---------------------------------------------------------------------------
// Causal GQA flash attention, fp16 MFMA, swapped operands; K/V LDS staging
// now DOUBLE-BUFFERED with counted waits: issue STAGE(t+1) before computing
// tile t; WAIT_VM(0) only after compute (loads land under compute);
// one raw s_barrier per tile. ntiles = 2qb+2 is even -> static 2-tile unroll.
// LDS 37 KB -> 4 blocks/CU.
// ---------------------------------------------------------------------------
__global__ __launch_bounds__(256) void attn_mfma_kernel(
    const ushort* __restrict__ Qh,   // [S][NH*HD] fp16, roped, *1/sqrt(HD)
    const ushort* __restrict__ Kh,   // [S][NKV*HD] fp16, roped
    const ushort* __restrict__ Vt,   // [NKV*HD][S] fp16 (transposed)
    ushort* __restrict__ AO)         // [S][NH*HD] fp16
{
    __shared__ ushort Ks0[32 * 128];           // swz ^((row&7)<<4)
    __shared__ ushort Ks1[32 * 128];
    __shared__ ushort Vs0[128 * 32];           // swz ^((dim&3)<<4)
    __shared__ ushort Vs1[128 * 32];
    __shared__ __align__(16) char PsB[4 * 1280];  // P: 16 rows x 80B per wave

    const int h  = blockIdx.x;
    const int qb = gridDim.y - 1 - blockIdx.y;
    const int s0 = qb * 64;
    const int t  = threadIdx.x;
    const int w  = t >> 6;
    const int l  = t & 63;
    const int lg = l >> 4;
    const int lr = l & 15;
    const int kvh = h >> 2;
    const int qw = s0 + w * 16;
    const int q  = qw + lr;          // this lane's q-row

    half8v qf[4];
#pragma unroll
    for (int d = 0; d < 4; ++d) {
        size_t off = (size_t)q * (NH * HD) + h * HD + d * 32 + lg * 8;
        qf[d] = *(const half8v*)&Qh[off];
    }

    f32x4 o[8];
#pragma unroll
    for (int i = 0; i < 8; ++i) o[i] = f32x4{0.f, 0.f, 0.f, 0.f};
    float m = -1e30f, lsum = 0.f;
    char* pw = PsB + w * 1280;

#define ATTN_STAGE(KB, VB, k0) { \
    _Pragma("unroll") \
    for (int i = 0; i < 2; ++i) { \
        int slot = w * 128 + i * 64 + l; \
        int mr = slot >> 4, c = slot & 15; \
        size_t goff = (size_t)((k0) + mr) * (NKV * HD) + kvh * HD + ((c ^ (mr & 7)) * 8); \
        gl_lds16(Kh + goff, (char*)(KB) + (w * 128 + i * 64) * 16); \
    } \
    _Pragma("unroll") \
    for (int i = 0; i < 2; ++i) { \
        int slot = w * 128 + i * 64 + l; \
        int dim = slot >> 2, c = slot & 3; \
        size_t goff = (size_t)(kvh * HD + dim) * S_LEN + (k0) + ((c ^ (dim & 3)) * 8); \
        gl_lds16(Vt + goff, (char*)(VB) + (w * 128 + i * 64) * 16); \
    } }

#define ATTN_TILE(KSF, VSS, k0) \
    if ((k0) <= qw + 15) { \
        f32x4 s_[2]; \
        s_[0] = f32x4{0.f, 0.f, 0.f, 0.f}; \
        s_[1] = f32x4{0.f, 0.f, 0.f, 0.f}; \
        _Pragma("unroll") \
        for (int d = 0; d < 4; ++d) { \
            _Pragma("unroll") \
            for (int nt2 = 0; nt2 < 2; ++nt2) { \
                int row = nt2 * 16 + lr; \
                int off = row * 256 + ((d * 64 + lg * 16) ^ ((row & 7) << 4)); \
                half8v kf = *(const half8v*)((const char*)(KSF) + off); \
                s_[nt2] = __builtin_amdgcn_mfma_f32_16x16x32_f16(kf, qf[d], s_[nt2], 0, 0, 0); \
            } \
        } \
        float sv[8]; \
        _Pragma("unroll") \
        for (int nt2 = 0; nt2 < 2; ++nt2) \
            _Pragma("unroll") \
            for (int r = 0; r < 4; ++r) { \
                int kv = (k0) + nt2 * 16 + lg * 4 + r; \
                sv[nt2 * 4 + r] = (kv <= q) ? s_[nt2][r] : -1e30f; \
            } \
        float mx = sv[0]; \
        _Pragma("unroll") \
        for (int j = 1; j < 8; ++j) mx = fmaxf(mx, sv[j]); \
        mx = fmaxf(mx, __shfl_xor(mx, 16)); \
        mx = fmaxf(mx, __shfl_xor(mx, 32)); \
        float mnew = fmaxf(m, mx); \
        float resc = __expf(m - mnew); \
        m = mnew; \
        float p_[8], ps = 0.f; \
        _Pragma("unroll") \
        for (int j = 0; j < 8; ++j) { p_[j] = __expf(sv[j] - mnew); ps += p_[j]; } \
        ps += __shfl_xor(ps, 16); \
        ps += __shfl_xor(ps, 32); \
        lsum = lsum * resc + ps; \
        _Pragma("unroll") \
        for (int dt = 0; dt < 8; ++dt) \
            _Pragma("unroll") \
            for (int r = 0; r < 4; ++r) o[dt][r] *= resc; \
        uint2 w0_ = {pk2(f2h(p_[0]), f2h(p_[1])), pk2(f2h(p_[2]), f2h(p_[3]))}; \
        uint2 w1_ = {pk2(f2h(p_[4]), f2h(p_[5])), pk2(f2h(p_[6]), f2h(p_[7]))}; \
        *(uint2*)(pw + lr * 80 + lg * 8)      = w0_; \
        *(uint2*)(pw + lr * 80 + 32 + lg * 8) = w1_; \
        asm volatile("s_waitcnt lgkmcnt(0)" ::: "memory"); \
        half8v pf = *(const half8v*)(pw + lr * 80 + lg * 16); \
        _Pragma("unroll") \
        for (int dt = 0; dt < 8; ++dt) { \
            int dim = dt * 16 + lr; \
            half8v vf = *(const half8v*)((const char*)(VSS) + dim * 64 + ((lg * 16) ^ ((dim & 3) << 4))); \
            o[dt] = __builtin_amdgcn_mfma_f32_16x16x32_f16(vf, pf, o[dt], 0, 0, 0); \
        } \
    }

    const int ntiles = qb * 2 + 2;   // always even

    // prologue: stage tile 0
    ATTN_STAGE(Ks0, Vs0, 0);
    WAIT_VM(0);
    RAW_BARRIER;

    for (int kt = 0; kt < ntiles; kt += 2) {
        // tile kt (bufs 0)
        if (kt + 1 < ntiles) ATTN_STAGE(Ks1, Vs1, (kt + 1) * 32);
        ATTN_TILE(Ks0, Vs0, kt * 32);
        WAIT_VM(0);
        RAW_BARRIER;
        // tile kt+1 (bufs 1)
        if (kt + 2 < ntiles) ATTN_STAGE(Ks0, Vs0, (kt + 2) * 32);
        ATTN_TILE(Ks1, Vs1, (kt + 1) * 32);
        WAIT_VM(0);
        RAW_BARRIER;
    }

    float inv = 1.f / lsum;
    ushort* dst = &AO[(size_t)q * (NH * HD) + h * HD];
#pragma unroll
    for (int dt = 0; dt < 8; ++dt) {
        uint2 ov = {pk2(f2h(o[dt][0] * inv), f2h(o[dt][1] * inv)),
                    pk2(f2h(o[dt][2] * inv), f2h(o[dt][3] * inv))};
        *(uint2*)(dst + dt * 16 + lg * 4) = ov;
    }
#undef ATTN_STAGE
#undef ATTN_TILE
}

// ---------------------------------------------------------------------------
extern "C" void kernel_launch(void* const* d_in, const int* in_sizes, int n_in,
                              void* d_out, int out_size, void* d_ws, size_t ws_size,
                              hipStream_t stream)
{
    const float* x    = (const float*)d_in[0];
    const float* cosb = (const float*)d_in[1];
    const float* sinb = (const float*)d_in[2];
    const float* q_sc = (const float*)d_in[3];
    const float* q_b  = (const float*)d_in[4];
    const float* k_sc = (const float*)d_in[5];
    const float* k_b  = (const float*)d_in[6];
    const float* v_sc = (const float*)d_in[7];
    const float* v_b  = (const float*)d_in[8];
    const float* o_sc = (const float*)d_in[9];
    const int* q_qw   = (const int*)d_in[10];
    const int* q_qz   = (const int*)d_in[11];
    const int* k_qw   = (const int*)d_in[12];
    const int* k_qz   = (const int*)d_in[13];
    const int* v_qw   = (const int*)d_in[14];
    const int* v_qz   = (const int*)d_in[15];
    const int* o_qw   = (const int*)d_in[16];
    const int* o_qz   = (const int*)d_in[17];
    float* out = (float*)d_out;

    // ws layout (MB):
    //   0:  Xf16 (10)  [aliased by AOf16 (16) after qkv7]
    //   16: Qf (16) | 32: Kf (4) | 36: Vrm (4) | 40: VfT (4)
    char* ws = (char*)d_ws;
    ushort* Xf   = (ushort*)ws;
    ushort* AOf  = (ushort*)ws;                                  // alias
    ushort* Qf   = (ushort*)(ws + (size_t)16 * 1024 * 1024);
    ushort* Kf   = (ushort*)(ws + (size_t)32 * 1024 * 1024);
    ushort* Vrm  = (ushort*)(ws + (size_t)36 * 1024 * 1024);
    ushort* VfT  = (ushort*)(ws + (size_t)40 * 1024 * 1024);

    xcvt_kernel<<<S_LEN, 320, 0, stream>>>(x, Xf);

    qkv7_kernel<<<768, 256, 0, stream>>>(
        Xf,
        q_qw, q_sc, q_qz, q_b,
        k_qw, k_sc, k_qz, k_b,
        v_qw, v_sc, v_qz, v_b,
        cosb, sinb, Qf, Kf, Vrm);

    vtrans_kernel<<<dim3(S_LEN / 64, (NKV * HD) / 64), 256, 0, stream>>>(Vrm, VfT);

    attn_mfma_kernel<<<dim3(NH, S_LEN / 64), 256, 0, stream>>>(Qf, Kf, VfT, AOf);

    oproj6_kernel<<<320, 256, 0, stream>>>(
        AOf, o_qw, o_sc, o_qz, out);
}

// Round 15
// 259.870 us; speedup vs baseline: 1.1053x; 1.0180x over previous
//
#include <hip/hip_runtime.h>
#include <hip/hip_bf16.h>
#include <cstdint>

#define S_LEN 2048
#define HIDDEN 2560
#define NH 32
#define NKV 8
#define HD 128
#define GS 128

typedef __attribute__((ext_vector_type(8))) _Float16 half8v;    // 8 x fp16
typedef __attribute__((ext_vector_type(2))) _Float16 half2v;    // 2 x fp16
typedef __attribute__((ext_vector_type(4))) float f32x4;
typedef unsigned int uint;
typedef unsigned short ushort;

__device__ inline ushort f2h(float f) {
    _Float16 h = (_Float16)f;
    return __builtin_bit_cast(ushort, h);
}
__device__ inline float h2f(ushort u) {
    return (float)__builtin_bit_cast(_Float16, u);
}
__device__ inline uint pk2(ushort a, ushort b) { return (uint)a | ((uint)b << 16); }

// async global->LDS, 16B per lane; lds base must be wave-uniform
__device__ __attribute__((always_inline)) inline void gl_lds16(const void* g, void* l) {
    __builtin_amdgcn_global_load_lds(
        (const __attribute__((address_space(1))) unsigned int*)g,
        (__attribute__((address_space(3))) unsigned int*)l, 16, 0, 0);
}

// counted-waitcnt barrier helpers (T3+T4): raw s_barrier, no vmcnt(0) drain
#define WAIT_LGKM0  asm volatile("s_waitcnt lgkmcnt(0)" ::: "memory")
#define WAIT_VM(N)  asm volatile("s_waitcnt vmcnt(" #N ")" ::: "memory")
#define RAW_BARRIER { __builtin_amdgcn_s_barrier(); __builtin_amdgcn_sched_barrier(0); }

// ---------------------------------------------------------------------------
// X -> fp16. One block per row, 320 thr x 8 els.
// ---------------------------------------------------------------------------
__global__ __launch_bounds__(320) void xcvt_kernel(
    const float* __restrict__ X, ushort* __restrict__ Xf)
{
    const int row = blockIdx.x;
    const int t   = threadIdx.x;
    const size_t base = (size_t)row * HIDDEN + t * 8;
    float4 a = *(const float4*)&X[base];
    float4 b = *(const float4*)&X[base + 4];
    uint4 hw = {pk2(f2h(a.x), f2h(a.y)), pk2(f2h(a.z), f2h(a.w)),
                pk2(f2h(b.x), f2h(b.y)), pk2(f2h(b.z), f2h(b.w))};
    *(uint4*)&Xf[base] = hw;
}

// ===========================================================================
// Fused Q/K/V AWQ-int4 MFMA GEMM, fp16 direct-scaled B, counted-vmcnt.
// B-unpack via v_perm_b32, but correction constants SPLIT (round-13 numerics):
//   e = (perm(y,x,sel) << 3) | 0x58005800   (exact fp16(128+n) pair)
//   w = pk_fma(e, sc2, M2) + Z2,  M2 = -128*sc (EXACT exp shift), Z2 = -z*sc
// ===========================================================================
__global__ __launch_bounds__(256) void qkv9_kernel(
    const ushort* __restrict__ Xf,
    const int* __restrict__ q_qw, const float* __restrict__ q_sc,
    const int* __restrict__ q_qz, const float* __restrict__ q_b,
    const int* __restrict__ k_qw, const float* __restrict__ k_sc,
    const int* __restrict__ k_qz, const float* __restrict__ k_b,
    const int* __restrict__ v_qw, const float* __restrict__ v_sc,
    const int* __restrict__ v_qz, const float* __restrict__ v_b,
    const float* __restrict__ cosb, const float* __restrict__ sinb,
    ushort* __restrict__ Qf, ushort* __restrict__ Kf,
    ushort* __restrict__ Vrm)
{
    __shared__ __align__(16) char LDSB[65536];
    ushort* A0 = (ushort*)(LDSB);
    ushort* A1 = (ushort*)(LDSB + 16384);
    ushort* B0 = (ushort*)(LDSB + 32768);
    ushort* B1 = (ushort*)(LDSB + 49152);

    const int t  = threadIdx.x;
    const int w  = t >> 6;        // 0..3
    const int l  = t & 63;
    const int lg = l >> 4;
    const int lr = l & 15;
    const int wr = w >> 1;        // M half
    const int wc = w & 1;         // N half
    const int K  = HIDDEN;

    const int bid = blockIdx.x;
    const int swz = (bid & 7) * 96 + (bid >> 3);
    const int nblk = swz % 48;
    const int m0   = (swz / 48) * 128;

    int region, nbase, Nw;
    const int* QW; const float* SC; const int* QZ; const float* BI;
    if (nblk < 32)      { region = 0; nbase = nblk * 128;        Nw = NH * HD;
                          QW = q_qw; SC = q_sc; QZ = q_qz; BI = q_b; }
    else if (nblk < 40) { region = 1; nbase = (nblk - 32) * 128; Nw = NKV * HD;
                          QW = k_qw; SC = k_sc; QZ = k_qz; BI = k_b; }
    else                { region = 2; nbase = (nblk - 40) * 128; Nw = NKV * HD;
                          QW = v_qw; SC = v_sc; QZ = v_qz; BI = v_b; }

    const int ldsAw = w * 1024;
    size_t aoff[4];
#pragma unroll
    for (int i = 0; i < 4; ++i) {
        int slot = i * 256 + t;
        int am = slot >> 3, ac = slot & 7;
        aoff[i] = (size_t)(m0 + am) * K + (size_t)((ac ^ (am & 7)) * 8);
    }
    const int bn  = t & 127;
    const int bk0 = (t >> 7) * 4;
    int bwoff[4];
#pragma unroll
    for (int j = 0; j < 4; ++j)
        bwoff[j] = (bn * 128 + (bk0 + j) * 16) ^ ((bn & 7) << 4);

    int ncm[4];
#pragma unroll
    for (int nf = 0; nf < 4; ++nf)
        ncm[nf] = wc * 32 + (nf & 1) * 16 + lr + ((nf & 2) ? 64 : 0);

    const int xorA = (lr & 7) << 4;
    int aroff[4][2], broff[4][2];
#pragma unroll
    for (int mf = 0; mf < 4; ++mf)
#pragma unroll
        for (int ks = 0; ks < 2; ++ks)
            aroff[mf][ks] = (((wr * 64 + mf * 16 + lr) * 128) + lg * 16 + ks * 64) ^ xorA;
#pragma unroll
    for (int nf = 0; nf < 4; ++nf)
#pragma unroll
        for (int ks = 0; ks < 2; ++ks)
            broff[nf][ks] = ((ncm[nf] * 128) + lg * 16 + ks * 64) ^ xorA;

    f32x4 macc[4][4];
#pragma unroll
    for (int mf = 0; mf < 4; ++mf)
#pragma unroll
        for (int nf = 0; nf < 4; ++nf) macc[mf][nf] = f32x4{0.f, 0.f, 0.f, 0.f};
    uint qr[4];
    float scf, zf;

#define QKV_QW(tile) { int g8 = (tile) * 8; int gg = (tile) >> 1; \
    _Pragma("unroll") \
    for (int j = 0; j < 4; ++j) \
        qr[j] = (uint)QW[(size_t)(g8 + bk0 + j) * Nw + nbase + bn]; \
    scf = SC[(size_t)gg * Nw + nbase + bn]; \
    zf  = (float)QZ[(size_t)gg * Nw + nbase + bn]; }

#define QKV_STAGE_A(AH, k0) { \
    gl_lds16(Xf + (k0) + aoff[0], (char*)(AH) + ldsAw); \
    gl_lds16(Xf + (k0) + aoff[1], (char*)(AH) + 4096 + ldsAw); \
    gl_lds16(Xf + (k0) + aoff[2], (char*)(AH) + 8192 + ldsAw); \
    gl_lds16(Xf + (k0) + aoff[3], (char*)(AH) + 12288 + ldsAw); }

#define QKV_BWRITE(BT) { \
    ushort sch = f2h(scf); \
    float schf = h2f(sch); \
    ushort msc = f2h(-128.0f * schf);   /* exact exponent shift */ \
    ushort nzs = f2h(-(zf * schf)); \
    half2v S2 = {__builtin_bit_cast(_Float16, sch), __builtin_bit_cast(_Float16, sch)}; \
    half2v M2 = {__builtin_bit_cast(_Float16, msc), __builtin_bit_cast(_Float16, msc)}; \
    half2v Z2 = {__builtin_bit_cast(_Float16, nzs), __builtin_bit_cast(_Float16, nzs)}; \
    _Pragma("unroll") \
    for (int j = 0; j < 4; ++j) { \
        uint q = qr[j]; \
        uint xn = q & 0x0F0F0F0Fu; \
        uint yn = (q >> 4) & 0x0F0F0F0Fu; \
        uint4 dw; \
        uint W0 = __builtin_amdgcn_perm(yn, xn, 0x0C040C00u); \
        uint W1 = __builtin_amdgcn_perm(yn, xn, 0x0C050C01u); \
        uint W2 = __builtin_amdgcn_perm(yn, xn, 0x0C060C02u); \
        uint W3 = __builtin_amdgcn_perm(yn, xn, 0x0C070C03u); \
        uint e0 = (W0 << 3) | 0x58005800u; \
        uint e1 = (W1 << 3) | 0x58005800u; \
        uint e2 = (W2 << 3) | 0x58005800u; \
        uint e3 = (W3 << 3) | 0x58005800u; \
        half2v w0 = __builtin_bit_cast(half2v, e0) * S2 + M2; w0 = w0 + Z2; \
        half2v w1 = __builtin_bit_cast(half2v, e1) * S2 + M2; w1 = w1 + Z2; \
        half2v w2 = __builtin_bit_cast(half2v, e2) * S2 + M2; w2 = w2 + Z2; \
        half2v w3 = __builtin_bit_cast(half2v, e3) * S2 + M2; w3 = w3 + Z2; \
        dw.x = __builtin_bit_cast(uint, w0); \
        dw.y = __builtin_bit_cast(uint, w1); \
        dw.z = __builtin_bit_cast(uint, w2); \
        dw.w = __builtin_bit_cast(uint, w3); \
        *(uint4*)((char*)(BT) + bwoff[j]) = dw; \
    } }

#define QKV_COMPUTE(AH, BT) { \
    _Pragma("unroll") \
    for (int ks = 0; ks < 2; ++ks) { \
        half8v av[4], bv[4]; \
        _Pragma("unroll") \
        for (int mf = 0; mf < 4; ++mf) \
            av[mf] = *(const half8v*)((const char*)(AH) + aroff[mf][ks]); \
        _Pragma("unroll") \
        for (int nf = 0; nf < 4; ++nf) \
            bv[nf] = *(const half8v*)((const char*)(BT) + broff[nf][ks]); \
        _Pragma("unroll") \
        for (int mf = 0; mf < 4; ++mf) \
            _Pragma("unroll") \
            for (int nf = 0; nf < 4; ++nf) \
                macc[mf][nf] = __builtin_amdgcn_mfma_f32_16x16x32_f16(av[mf], bv[nf], macc[mf][nf], 0, 0, 0); \
    } }

    QKV_QW(0);
    QKV_BWRITE(B0);
    QKV_STAGE_A(A0, 0);
    QKV_QW(1);
    WAIT_LGKM0;
    WAIT_VM(6);
    RAW_BARRIER;

    for (int g = 0; g < 19; ++g) {
        QKV_STAGE_A(A1, (2 * g + 1) * 64);
        QKV_COMPUTE(A0, B0);
        QKV_BWRITE(B1);
        QKV_QW(2 * g + 2);
        WAIT_LGKM0;
        WAIT_VM(6);
        RAW_BARRIER;
        QKV_STAGE_A(A0, (2 * g + 2) * 64);
        QKV_COMPUTE(A1, B1);
        QKV_BWRITE(B0);
        QKV_QW(2 * g + 3);
        WAIT_LGKM0;
        WAIT_VM(6);
        RAW_BARRIER;
    }
    QKV_STAGE_A(A1, 39 * 64);
    QKV_COMPUTE(A0, B0);
    QKV_BWRITE(B1);
    WAIT_LGKM0;
    WAIT_VM(0);
    RAW_BARRIER;
    QKV_COMPUTE(A1, B1);

#pragma unroll
    for (int nf = 0; nf < 4; ++nf) {
        float bv = BI[nbase + ncm[nf]];
#pragma unroll
        for (int mf = 0; mf < 4; ++mf)
#pragma unroll
            for (int r = 0; r < 4; ++r) macc[mf][nf][r] += bv;
    }

    if (region == 2) {
#pragma unroll
        for (int mf = 0; mf < 4; ++mf)
#pragma unroll
            for (int r = 0; r < 4; ++r) {
                int row = m0 + wr * 64 + mf * 16 + lg * 4 + r;
#pragma unroll
                for (int nf = 0; nf < 4; ++nf)
                    Vrm[(size_t)row * (NKV * HD) + nbase + ncm[nf]] = f2h(macc[mf][nf][r]);
            }
    } else {
        ushort* OF = (region == 0) ? Qf : Kf;
        const int No = (region == 0) ? NH * HD : NKV * HD;
        const float osc = (region == 0) ? 0.08838834764831845f : 1.0f;
#pragma unroll
        for (int mf = 0; mf < 4; ++mf)
#pragma unroll
            for (int r = 0; r < 4; ++r) {
                int row = m0 + wr * 64 + mf * 16 + lg * 4 + r;
                const float* cb = &cosb[(size_t)row * HD];
                const float* sb = &sinb[(size_t)row * HD];
#pragma unroll
                for (int nf = 0; nf < 2; ++nf) {
                    int d = wc * 32 + nf * 16 + lr;           // 0..63
                    float a = macc[mf][nf][r];
                    float b = macc[mf][nf + 2][r];
                    float o1 = (a * cb[d]      - b * sb[d])      * osc;
                    float o2 = (b * cb[d + 64] + a * sb[d + 64]) * osc;
                    OF[(size_t)row * No + nbase + d]      = f2h(o1);
                    OF[(size_t)row * No + nbase + d + 64] = f2h(o2);
                }
            }
    }
#undef QKV_QW
#undef QKV_STAGE_A
#undef QKV_BWRITE
#undef QKV_COMPUTE
}

// ---------------------------------------------------------------------------
// V transpose: Vrm [S][1024] fp16 -> VfT [1024][S]. 64x64 LDS tiles.
// ---------------------------------------------------------------------------
__global__ __launch_bounds__(256) void vtrans_kernel(
    const ushort* __restrict__ Vrm, ushort* __restrict__ VfT)
{
    __shared__ ushort Ts[64][65];
    const int s0 = blockIdx.x * 64;
    const int n0 = blockIdx.y * 64;
    const int t  = threadIdx.x;
    {
        int r = t >> 2, c0 = (t & 3) * 16;
        uint4 v0 = *(const uint4*)&Vrm[(size_t)(s0 + r) * (NKV * HD) + n0 + c0];
        uint4 v1 = *(const uint4*)&Vrm[(size_t)(s0 + r) * (NKV * HD) + n0 + c0 + 8];
        const ushort* pv = (const ushort*)&v0;
#pragma unroll
        for (int j = 0; j < 8; ++j) Ts[r][c0 + j] = pv[j];
        pv = (const ushort*)&v1;
#pragma unroll
        for (int j = 0; j < 8; ++j) Ts[r][c0 + 8 + j] = pv[j];
    }
    __syncthreads();
    {
        int rn = t >> 2, cs0 = (t & 3) * 16;
        ushort ob[16];
#pragma unroll
        for (int j = 0; j < 16; ++j) ob[j] = Ts[cs0 + j][rn];
        ushort* dst = &VfT[(size_t)(n0 + rn) * S_LEN + s0 + cs0];
        *(uint4*)dst = ((uint4*)ob)[0];
        *(uint4*)(dst + 8) = ((uint4*)ob)[1];
    }
}

// ===========================================================================
// O-projection, fp16 direct-scaled B, counted-vmcnt; perm unpack + split
// constants (round-13 numerics).
// ===========================================================================
__global__ __launch_bounds__(256) void oproj8_kernel(
    const ushort* __restrict__ Xb, const int* __restrict__ QW,
    const float* __restrict__ SC, const int* __restrict__ QZ,
    float* __restrict__ Y)
{
    __shared__ __align__(16) char LDSB[65536];
    ushort* A0 = (ushort*)(LDSB);
    ushort* A1 = (ushort*)(LDSB + 16384);
    ushort* B0 = (ushort*)(LDSB + 32768);
    ushort* B1 = (ushort*)(LDSB + 49152);

    const int t  = threadIdx.x;
    const int w  = t >> 6;
    const int l  = t & 63;
    const int lg = l >> 4;
    const int lr = l & 15;
    const int wr = w >> 1;
    const int wc = w & 1;
    const int K  = NH * HD;      // 4096
    const int N  = HIDDEN;       // 2560

    const int bid = blockIdx.x;
    const int swz = (bid & 7) * 40 + (bid >> 3);   // 320 = 8*40
    const int n0  = (swz % 20) * 128;
    const int m0  = (swz / 20) * 128;

    const int ldsAw = w * 1024;
    size_t aoff[4];
#pragma unroll
    for (int i = 0; i < 4; ++i) {
        int slot = i * 256 + t;
        int am = slot >> 3, ac = slot & 7;
        aoff[i] = (size_t)(m0 + am) * K + (size_t)((ac ^ (am & 7)) * 8);
    }
    const int bn  = t & 127;
    const int bk0 = (t >> 7) * 4;
    int bwoff[4];
#pragma unroll
    for (int j = 0; j < 4; ++j)
        bwoff[j] = (bn * 128 + (bk0 + j) * 16) ^ ((bn & 7) << 4);

    const int xorA = (lr & 7) << 4;
    int aroff[4][2], broff[4][2];
#pragma unroll
    for (int mf = 0; mf < 4; ++mf)
#pragma unroll
        for (int ks = 0; ks < 2; ++ks)
            aroff[mf][ks] = (((wr * 64 + mf * 16 + lr) * 128) + lg * 16 + ks * 64) ^ xorA;
#pragma unroll
    for (int nf = 0; nf < 4; ++nf)
#pragma unroll
        for (int ks = 0; ks < 2; ++ks)
            broff[nf][ks] = (((wc * 64 + nf * 16 + lr) * 128) + lg * 16 + ks * 64) ^ xorA;

    f32x4 macc[4][4];
#pragma unroll
    for (int mf = 0; mf < 4; ++mf)
#pragma unroll
        for (int nf = 0; nf < 4; ++nf) macc[mf][nf] = f32x4{0.f, 0.f, 0.f, 0.f};
    uint qr[4];
    float scf, zf;

#define OP_QW(tile) { int g8 = (tile) * 8; int gg = (tile) >> 1; \
    _Pragma("unroll") \
    for (int j = 0; j < 4; ++j) \
        qr[j] = (uint)QW[(size_t)(g8 + bk0 + j) * N + n0 + bn]; \
    scf = SC[(size_t)gg * N + n0 + bn]; \
    zf  = (float)QZ[(size_t)gg * N + n0 + bn]; }

#define OP_STAGE_A(AH, k0) { \
    gl_lds16(Xb + (k0) + aoff[0], (char*)(AH) + ldsAw); \
    gl_lds16(Xb + (k0) + aoff[1], (char*)(AH) + 4096 + ldsAw); \
    gl_lds16(Xb + (k0) + aoff[2], (char*)(AH) + 8192 + ldsAw); \
    gl_lds16(Xb + (k0) + aoff[3], (char*)(AH) + 12288 + ldsAw); }

#define OP_BWRITE(BT) { \
    ushort sch = f2h(scf); \
    float schf = h2f(sch); \
    ushort msc = f2h(-128.0f * schf); \
    ushort nzs = f2h(-(zf * schf)); \
    half2v S2 = {__builtin_bit_cast(_Float16, sch), __builtin_bit_cast(_Float16, sch)}; \
    half2v M2 = {__builtin_bit_cast(_Float16, msc), __builtin_bit_cast(_Float16, msc)}; \
    half2v Z2 = {__builtin_bit_cast(_Float16, nzs), __builtin_bit_cast(_Float16, nzs)}; \
    _Pragma("unroll") \
    for (int j = 0; j < 4; ++j) { \
        uint q = qr[j]; \
        uint xn = q & 0x0F0F0F0Fu; \
        uint yn = (q >> 4) & 0x0F0F0F0Fu; \
        uint4 dw; \
        uint W0 = __builtin_amdgcn_perm(yn, xn, 0x0C040C00u); \
        uint W1 = __builtin_amdgcn_perm(yn, xn, 0x0C050C01u); \
        uint W2 = __builtin_amdgcn_perm(yn, xn, 0x0C060C02u); \
        uint W3 = __builtin_amdgcn_perm(yn, xn, 0x0C070C03u); \
        uint e0 = (W0 << 3) | 0x58005800u; \
        uint e1 = (W1 << 3) | 0x58005800u; \
        uint e2 = (W2 << 3) | 0x58005800u; \
        uint e3 = (W3 << 3) | 0x58005800u; \
        half2v w0 = __builtin_bit_cast(half2v, e0) * S2 + M2; w0 = w0 + Z2; \
        half2v w1 = __builtin_bit_cast(half2v, e1) * S2 + M2; w1 = w1 + Z2; \
        half2v w2 = __builtin_bit_cast(half2v, e2) * S2 + M2; w2 = w2 + Z2; \
        half2v w3 = __builtin_bit_cast(half2v, e3) * S2 + M2; w3 = w3 + Z2; \
        dw.x = __builtin_bit_cast(uint, w0); \
        dw.y = __builtin_bit_cast(uint, w1); \
        dw.z = __builtin_bit_cast(uint, w2); \
        dw.w = __builtin_bit_cast(uint, w3); \
        *(uint4*)((char*)(BT) + bwoff[j]) = dw; \
    } }

#define OP_COMPUTE(AH, BT) { \
    _Pragma("unroll") \
    for (int ks = 0; ks < 2; ++ks) { \
        half8v av[4], bv[4]; \
        _Pragma("unroll") \
        for (int mf = 0; mf < 4; ++mf) \
            av[mf] = *(const half8v*)((const char*)(AH) + aroff[mf][ks]); \
        _Pragma("unroll") \
        for (int nf = 0; nf < 4; ++nf) \
            bv[nf] = *(const half8v*)((const char*)(BT) + broff[nf][ks]); \
        _Pragma("unroll") \
        for (int mf = 0; mf < 4; ++mf) \
            _Pragma("unroll") \
            for (int nf = 0; nf < 4; ++nf) \
                macc[mf][nf] = __builtin_amdgcn_mfma_f32_16x16x32_f16(av[mf], bv[nf], macc[mf][nf], 0, 0, 0); \
    } }

    OP_QW(0);
    OP_BWRITE(B0);
    OP_STAGE_A(A0, 0);
    OP_QW(1);
    WAIT_LGKM0;
    WAIT_VM(6);
    RAW_BARRIER;

    for (int g = 0; g < 31; ++g) {
        OP_STAGE_A(A1, (2 * g + 1) * 64);
        OP_COMPUTE(A0, B0);
        OP_BWRITE(B1);
        OP_QW(2 * g + 2);
        WAIT_LGKM0;
        WAIT_VM(6);
        RAW_BARRIER;
        OP_STAGE_A(A0, (2 * g + 2) * 64);
        OP_COMPUTE(A1, B1);
        OP_BWRITE(B0);
        OP_QW(2 * g + 3);
        WAIT_LGKM0;
        WAIT_VM(6);
        RAW_BARRIER;
    }
    OP_STAGE_A(A1, 63 * 64);
    OP_COMPUTE(A0, B0);
    OP_BWRITE(B1);
    WAIT_LGKM0;
    WAIT_VM(0);
    RAW_BARRIER;
    OP_COMPUTE(A1, B1);

#pragma unroll
    for (int mf = 0; mf < 4; ++mf)
#pragma unroll
        for (int r = 0; r < 4; ++r) {
            int row = m0 + wr * 64 + mf * 16 + lg * 4 + r;
#pragma unroll
            for (int nf = 0; nf < 4; ++nf)
                Y[(size_t)row * N + n0 + wc * 64 + nf * 16 + lr] = macc[mf][nf][r];
        }
#undef OP_QW
#undef OP_STAGE_A
#undef OP_BWRITE
#undef OP_COMPUTE
}

// ---------------------------------------------------------------------------
// Causal GQA flash attention, fp16 MFMA, swapped operands; double-buffered
// K/V staging with counted waits (unchanged round 13).
// ---------------------------------------------------------------------------
__global__ __launch_bounds__(256) void attn_mfma_kernel(
    const ushort* __restrict__ Qh,   // [S][NH*HD] fp16, roped, *1/sqrt(HD)
    const ushort* __restrict__ Kh,   // [S][NKV*HD] fp16, roped
    const ushort* __restrict__ Vt,   // [NKV*HD][S] fp16 (transposed)
    ushort* __restrict__ AO)         // [S][NH*HD] fp16
{
    __shared__ ushort Ks0[32 * 128];           // swz ^((row&7)<<4)
    __shared__ ushort Ks1[32 * 128];
    __shared__ ushort Vs0[128 * 32];           // swz ^((dim&3)<<4)
    __shared__ ushort Vs1[128 * 32];
    __shared__ __align__(16) char PsB[4 * 1280];  // P: 16 rows x 80B per wave

    const int h  = blockIdx.x;
    const int qb = gridDim.y - 1 - blockIdx.y;
    const int s0 = qb * 64;
    const int t  = threadIdx.x;
    const int w  = t >> 6;
    const int l  = t & 63;
    const int lg = l >> 4;
    const int lr = l & 15;
    const int kvh = h >> 2;
    const int qw = s0 + w * 16;
    const int q  = qw + lr;          // this lane's q-row

    half8v qf[4];
#pragma unroll
    for (int d = 0; d < 4; ++d) {
        size_t off = (size_t)q * (NH * HD) + h * HD + d * 32 + lg * 8;
        qf[d] = *(const half8v*)&Qh[off];
    }

    f32x4 o[8];
#pragma unroll
    for (int i = 0; i < 8; ++i) o[i] = f32x4{0.f, 0.f, 0.f, 0.f};
    float m = -1e30f, lsum = 0.f;
    char* pw = PsB + w * 1280;

#define ATTN_STAGE(KB, VB, k0) { \
    _Pragma("unroll") \
    for (int i = 0; i < 2; ++i) { \
        int slot = w * 128 + i * 64 + l; \
        int mr = slot >> 4, c = slot & 15; \
        size_t goff = (size_t)((k0) + mr) * (NKV * HD) + kvh * HD + ((c ^ (mr & 7)) * 8); \
        gl_lds16(Kh + goff, (char*)(KB) + (w * 128 + i * 64) * 16); \
    } \
    _Pragma("unroll") \
    for (int i = 0; i < 2; ++i) { \
        int slot = w * 128 + i * 64 + l; \
        int dim = slot >> 2, c = slot & 3; \
        size_t goff = (size_t)(kvh * HD + dim) * S_LEN + (k0) + ((c ^ (dim & 3)) * 8); \
        gl_lds16(Vt + goff, (char*)(VB) + (w * 128 + i * 64) * 16); \
    } }

#define ATTN_TILE(KSF, VSS, k0) \
    if ((k0) <= qw + 15) { \
        f32x4 s_[2]; \
        s_[0] = f32x4{0.f, 0.f, 0.f, 0.f}; \
        s_[1] = f32x4{0.f, 0.f, 0.f, 0.f}; \
        _Pragma("unroll") \
        for (int d = 0; d < 4; ++d) { \
            _Pragma("unroll") \
            for (int nt2 = 0; nt2 < 2; ++nt2) { \
                int row = nt2 * 16 + lr; \
                int off = row * 256 + ((d * 64 + lg * 16) ^ ((row & 7) << 4)); \
                half8v kf = *(const half8v*)((const char*)(KSF) + off); \
                s_[nt2] = __builtin_amdgcn_mfma_f32_16x16x32_f16(kf, qf[d], s_[nt2], 0, 0, 0); \
            } \
        } \
        float sv[8]; \
        _Pragma("unroll") \
        for (int nt2 = 0; nt2 < 2; ++nt2) \
            _Pragma("unroll") \
            for (int r = 0; r < 4; ++r) { \
                int kv = (k0) + nt2 * 16 + lg * 4 + r; \
                sv[nt2 * 4 + r] = (kv <= q) ? s_[nt2][r] : -1e30f; \
            } \
        float mx = sv[0]; \
        _Pragma("unroll") \
        for (int j = 1; j < 8; ++j) mx = fmaxf(mx, sv[j]); \
        mx = fmaxf(mx, __shfl_xor(mx, 16)); \
        mx = fmaxf(mx, __shfl_xor(mx, 32)); \
        float mnew = fmaxf(m, mx); \
        float resc = __expf(m - mnew); \
        m = mnew; \
        float p_[8], ps = 0.f; \
        _Pragma("unroll") \
        for (int j = 0; j < 8; ++j) { p_[j] = __expf(sv[j] - mnew); ps += p_[j]; } \
        ps += __shfl_xor(ps, 16); \
        ps += __shfl_xor(ps, 32); \
        lsum = lsum * resc + ps; \
        _Pragma("unroll") \
        for (int dt = 0; dt < 8; ++dt) \
            _Pragma("unroll") \
            for (int r = 0; r < 4; ++r) o[dt][r] *= resc; \
        uint2 w0_ = {pk2(f2h(p_[0]), f2h(p_[1])), pk2(f2h(p_[2]), f2h(p_[3]))}; \
        uint2 w1_ = {pk2(f2h(p_[4]), f2h(p_[5])), pk2(f2h(p_[6]), f2h(p_[7]))}; \
        *(uint2*)(pw + lr * 80 + lg * 8)      = w0_; \
        *(uint2*)(pw + lr * 80 + 32 + lg * 8) = w1_; \
        asm volatile("s_waitcnt lgkmcnt(0)" ::: "memory"); \
        half8v pf = *(const half8v*)(pw + lr * 80 + lg * 16); \
        _Pragma("unroll") \
        for (int dt = 0; dt < 8; ++dt) { \
            int dim = dt * 16 + lr; \
            half8v vf = *(const half8v*)((const char*)(VSS) + dim * 64 + ((lg * 16) ^ ((dim & 3) << 4))); \
            o[dt] = __builtin_amdgcn_mfma_f32_16x16x32_f16(vf, pf, o[dt], 0, 0, 0); \
        } \
    }

    const int ntiles = qb * 2 + 2;   // always even

    ATTN_STAGE(Ks0, Vs0, 0);
    WAIT_VM(0);
    RAW_BARRIER;

    for (int kt = 0; kt < ntiles; kt += 2) {
        if (kt + 1 < ntiles) ATTN_STAGE(Ks1, Vs1, (kt + 1) * 32);
        ATTN_TILE(Ks0, Vs0, kt * 32);
        WAIT_VM(0);
        RAW_BARRIER;
        if (kt + 2 < ntiles) ATTN_STAGE(Ks0, Vs0, (kt + 2) * 32);
        ATTN_TILE(Ks1, Vs1, (kt + 1) * 32);
        WAIT_VM(0);
        RAW_BARRIER;
    }

    float inv = 1.f / lsum;
    ushort* dst = &AO[(size_t)q * (NH * HD) + h * HD];
#pragma unroll
    for (int dt = 0; dt < 8; ++dt) {
        uint2 ov = {pk2(f2h(o[dt][0] * inv), f2h(o[dt][1] * inv)),
                    pk2(f2h(o[dt][2] * inv), f2h(o[dt][3] * inv))};
        *(uint2*)(dst + dt * 16 + lg * 4) = ov;
    }
#undef ATTN_STAGE
#undef ATTN_TILE
}

// ---------------------------------------------------------------------------
extern "C" void kernel_launch(void* const* d_in, const int* in_sizes, int n_in,
                              void* d_out, int out_size, void* d_ws, size_t ws_size,
                              hipStream_t stream)
{
    const float* x    = (const float*)d_in[0];
    const float* cosb = (const float*)d_in[1];
    const float* sinb = (const float*)d_in[2];
    const float* q_sc = (const float*)d_in[3];
    const float* q_b  = (const float*)d_in[4];
    const float* k_sc = (const float*)d_in[5];
    const float* k_b  = (const float*)d_in[6];
    const float* v_sc = (const float*)d_in[7];
    const float* v_b  = (const float*)d_in[8];
    const float* o_sc = (const float*)d_in[9];
    const int* q_qw   = (const int*)d_in[10];
    const int* q_qz   = (const int*)d_in[11];
    const int* k_qw   = (const int*)d_in[12];
    const int* k_qz   = (const int*)d_in[13];
    const int* v_qw   = (const int*)d_in[14];
    const int* v_qz   = (const int*)d_in[15];
    const int* o_qw   = (const int*)d_in[16];
    const int* o_qz   = (const int*)d_in[17];
    float* out = (float*)d_out;

    // ws layout (MB):
    //   0:  Xf16 (10)  [aliased by AOf16 (16) after qkv9]
    //   16: Qf (16) | 32: Kf (4) | 36: Vrm (4) | 40: VfT (4)
    char* ws = (char*)d_ws;
    ushort* Xf   = (ushort*)ws;
    ushort* AOf  = (ushort*)ws;                                  // alias
    ushort* Qf   = (ushort*)(ws + (size_t)16 * 1024 * 1024);
    ushort* Kf   = (ushort*)(ws + (size_t)32 * 1024 * 1024);
    ushort* Vrm  = (ushort*)(ws + (size_t)36 * 1024 * 1024);
    ushort* VfT  = (ushort*)(ws + (size_t)40 * 1024 * 1024);

    xcvt_kernel<<<S_LEN, 320, 0, stream>>>(x, Xf);

    qkv9_kernel<<<768, 256, 0, stream>>>(
        Xf,
        q_qw, q_sc, q_qz, q_b,
        k_qw, k_sc, k_qz, k_b,
        v_qw, v_sc, v_qz, v_b,
        cosb, sinb, Qf, Kf, Vrm);

    vtrans_kernel<<<dim3(S_LEN / 64, (NKV * HD) / 64), 256, 0, stream>>>(Vrm, VfT);

    attn_mfma_kernel<<<dim3(NH, S_LEN / 64), 256, 0, stream>>>(Qf, Kf, VfT, AOf);

    oproj8_kernel<<<320, 256, 0, stream>>>(
        AOf, o_qw, o_sc, o_qz, out);
}